// Round 18
// baseline (154.030 us; speedup 1.0000x reference)
//
#include <hip/hip_runtime.h>
#include <hip/hip_bf16.h>
#include <cstdint>
#include <cstddef>

#define NH   16
#define HD   64
#define CD   1024
#define HARM 32
#define BSZ  2
#define LSEQ 2048
#define NROW (BSZ*LSEQ)   // 4096

typedef __attribute__((ext_vector_type(8))) short short8;     // 8 bf16 (A/B frag)
typedef __attribute__((ext_vector_type(16))) float float16v;  // 32x32 C frag

__device__ inline ushort bf16u(float f) {
    __hip_bfloat16 h = __float2bfloat16(f);
    return *(ushort*)&h;
}
__device__ inline float ubf(ushort u) {
    return __uint_as_float((unsigned)u << 16);
}
__device__ inline unsigned pk2(float a, float b) {
    return (unsigned)bf16u(a) | ((unsigned)bf16u(b) << 16);
}
// C-frag register r -> row offset within 32-row tile
__device__ inline int crow(int r, int half) { return (r & 3) + 8 * (r >> 2) + 4 * half; }

union S8U { short8 v; uint2 u[2]; };

// pi-permuted operand frag: raw packed C-frag regs for 16-k chunk cc.
// Slot (h,e) holds k = (e&3)+8*(e>>2)+4h (the involution pi). Valid as an
// MFMA A/B operand whenever the OTHER operand carries the same pi in its
// k-slots (pre-baked into weight tiles at prep, or raw C-frag on both sides).
__device__ inline short8 pk_frag(const unsigned* pk, int cc) {
    S8U o;
    o.u[0] = make_uint2(pk[4 * cc + 0], pk[4 * cc + 1]);
    o.u[1] = make_uint2(pk[4 * cc + 2], pk[4 * cc + 3]);
    return o.v;
}

// ---------------------------------------------------------------------------
// prep: fragment-tile all weights.
//   bF proj 0..2: STANDARD slot order (pairs with x-chunks in res_part).
//   bF proj 3, wqkvF, wobF: pi-permuted slot order (pair with raw C-frags).
// ---------------------------------------------------------------------------
__global__ void prep_kern(const float* __restrict__ bq, const float* __restrict__ bk,
                          const float* __restrict__ bv, const float* __restrict__ bo,
                          const float* __restrict__ pq, const float* __restrict__ aq,
                          const float* __restrict__ pk, const float* __restrict__ ak,
                          const float* __restrict__ pv, const float* __restrict__ av,
                          const float* __restrict__ po, const float* __restrict__ ao,
                          ushort* __restrict__ bF, ushort* __restrict__ wqkvF,
                          ushort* __restrict__ wobF) {
    const float QSCALE = 0.125f * 1.44269504088896340736f;  // hd^-0.5 * log2e
    unsigned tid = blockIdx.x * 256 + threadIdx.x;
    if (tid < 16384) {                 // bF
        unsigned l31 = tid & 31, h = (tid >> 5) & 1, kc = (tid >> 6) & 63, proj = tid >> 12;
        const float* bp = (proj == 0) ? bq : (proj == 1) ? bk : (proj == 2) ? bv : bo;
        const float* s = bp + (size_t)l31 * CD + kc * 16;
        // proj 3 permuted: elements {4h..4h+3, 8+4h..8+4h+3}; else {8h..8h+7}
        unsigned o0 = (proj == 3) ? h * 4 : h * 8;
        unsigned o1 = o0 + ((proj == 3) ? 8 : 4);
        float4 f0 = *(const float4*)(s + o0), f1 = *(const float4*)(s + o1);
        S8U o;
        o.u[0] = make_uint2(pk2(f0.x, f0.y), pk2(f0.z, f0.w));
        o.u[1] = make_uint2(pk2(f1.x, f1.y), pk2(f1.z, f1.w));
        *(short8*)(bF + (size_t)tid * 8) = o.v;
        return;
    }
    if (tid < 28672) {                 // wqkvF (pi-permuted harmonic slots)
        unsigned i = tid - 16384;
        unsigned l31 = i & 31, h = (i >> 5) & 1, kc2 = (i >> 6) & 1;
        unsigned ntp = (i >> 7) & 31, proj = i >> 12;
        const float* ph = (proj == 0) ? pq : (proj == 1) ? pk : pv;
        const float* am = (proj == 0) ? aq : (proj == 1) ? ak : av;
        float sc = (proj == 0) ? QSCALE : 1.0f;
        size_t s = (size_t)(ntp * 32 + l31) * HARM + kc2 * 16 + h * 4;
        float4 p0 = *(const float4*)(ph + s), p1 = *(const float4*)(ph + s + 8);
        float4 a0 = *(const float4*)(am + s), a1 = *(const float4*)(am + s + 8);
        S8U o;
        o.u[0] = make_uint2(pk2(a0.x * cosf(p0.x) * sc, a0.y * cosf(p0.y) * sc),
                            pk2(a0.z * cosf(p0.z) * sc, a0.w * cosf(p0.w) * sc));
        o.u[1] = make_uint2(pk2(a1.x * cosf(p1.x) * sc, a1.y * cosf(p1.y) * sc),
                            pk2(a1.z * cosf(p1.z) * sc, a1.w * cosf(p1.w) * sc));
        *(short8*)(wqkvF + (size_t)i * 8) = o.v;
        return;
    }
    {                                  // wobF (pi-permuted harmonic slots)
        unsigned i = tid - 28672;      // 4096
        unsigned l31 = i & 31, h = (i >> 5) & 1, kc2 = (i >> 6) & 1, nt = i >> 7;
        size_t s = (size_t)(nt * 32 + l31) * HARM + kc2 * 16 + h * 4;
        float4 p0 = *(const float4*)(po + s), p1 = *(const float4*)(po + s + 8);
        float4 a0 = *(const float4*)(ao + s), a1 = *(const float4*)(ao + s + 8);
        S8U o;
        o.u[0] = make_uint2(pk2(a0.x * cosf(p0.x), a0.y * cosf(p0.y)),
                            pk2(a0.z * cosf(p0.z), a0.w * cosf(p0.w)));
        o.u[1] = make_uint2(pk2(a1.x * cosf(p1.x), a1.y * cosf(p1.y)),
                            pk2(a1.z * cosf(p1.z), a1.w * cosf(p1.w)));
        *(short8*)(wobF + (size_t)i * 8) = o.v;
    }
}

// ---------------------------------------------------------------------------
// res_part: unchanged (verified).  bF proj 0..2 standard layout.
//   respart[kseg][rg][p][r][lane]  fp32, 6 MB total
// ---------------------------------------------------------------------------
__global__ __launch_bounds__(256) void res_part_kern(const float* __restrict__ x,
                                                     const ushort* __restrict__ bF,
                                                     float* __restrict__ respart) {
    __shared__ ushort xs[32 * 256];          // 16 KB
    __shared__ float red[4 * 16 * 64];       // 16 KB
    const int t = threadIdx.x, wave = t >> 6, lane = t & 63;
    const int l31 = lane & 31, h = lane >> 5;
    const int kseg = blockIdx.x & 3, rg = blockIdx.x >> 2;
    const int n0 = rg * 32;

#pragma unroll
    for (int i = 0; i < 8; i++) {
        int idx = i * 256 + t, row = idx >> 6, c4 = idx & 63;
        float4 v = *(const float4*)(x + (size_t)(n0 + row) * CD + kseg * 256 + c4 * 4);
        int chunk = (c4 >> 1) ^ (row & 15), sub = c4 & 1;
        *(ushort4*)(&xs[row * 256 + chunk * 8 + sub * 4]) =
            make_ushort4(bf16u(v.x), bf16u(v.y), bf16u(v.z), bf16u(v.w));
    }
    __syncthreads();

    float16v resC[3] = {};
#pragma unroll
    for (int kci = 0; kci < 4; kci++) {
        int c = wave * 8 + kci * 2 + h;
        short8 bx = *(const short8*)(&xs[l31 * 256 + (c ^ (l31 & 15)) * 8]);
        int kcg = kseg * 16 + wave * 4 + kci;
#pragma unroll
        for (int p = 0; p < 3; p++) {
            short8 a = *(const short8*)(bF + ((size_t)((p * 64 + kcg) * 2 + h) * 32 + l31) * 8);
            resC[p] = __builtin_amdgcn_mfma_f32_32x32x16_bf16(a, bx, resC[p], 0, 0, 0);
        }
    }
    float* outb = respart + ((size_t)(kseg * 128 + rg) * 3) * 1024;
    for (int p = 0; p < 3; p++) {
        __syncthreads();
#pragma unroll
        for (int r = 0; r < 16; r++) red[wave * 1024 + r * 64 + lane] = resC[p][r];
        __syncthreads();
#pragma unroll
        for (int i = 0; i < 4; i++) {
            int e = i * 256 + t;
            outb[p * 1024 + e] = (red[e] + red[1024 + e]) + (red[2048 + e] + red[3072 + e]);
        }
    }
}

// ---------------------------------------------------------------------------
// rp_kern: kseg-reduce + bf16-pack the rf table ONCE (verified round 8).
// ---------------------------------------------------------------------------
__global__ __launch_bounds__(256) void rp_kern(const float* __restrict__ respart,
                                               unsigned* __restrict__ rfbuf) {
    const int tid = blockIdx.x * 256 + threadIdx.x;     // 49152 total
    const int rest = tid / 384, u = tid % 384;
    const int p = u >> 7, cc = (u >> 6) & 1, lane = u & 63;

    const float* base = respart + ((size_t)rest * 3 + p) * 1024 + cc * 512 + lane;
    unsigned w[4];
#pragma unroll
    for (int q = 0; q < 4; q++) {
        const float* pa = base + (2 * q) * 64;
        const float* pb = pa + 64;
        float a = (pa[0] + pa[393216]) + (pa[2 * 393216] + pa[3 * 393216]);
        float bv_ = (pb[0] + pb[393216]) + (pb[2 * 393216] + pb[3 * 393216]);
        w[q] = pk2(a, bv_);
    }
    *(uint4*)(rfbuf + (size_t)rest * 1536 + ((p * 2 + cc) * 64 + lane) * 4) =
        make_uint4(w[0], w[1], w[2], w[3]);
}

// ---------------------------------------------------------------------------
// qkv v4: pure phase-2 (verified round 8).
// ---------------------------------------------------------------------------
__global__ __launch_bounds__(256) void qkv_kern(const unsigned* __restrict__ rfbuf,
                                                const ushort* __restrict__ wqkvF,
                                                ushort* __restrict__ qtile,
                                                ushort* __restrict__ ktile,
                                                ushort* __restrict__ vtile) {
    const int t = threadIdx.x, wave = t >> 6, lane = t & 63;
    const int l31 = lane & 31, h = lane >> 5;
    const int ntg = blockIdx.x % 24, rest = blockIdx.x / 24;
    const int b = rest >> 6, l0q = rest & 63;
    const int nt = ntg * 4 + wave;               // 0..95
    const int proj = nt >> 5, ntp = nt & 31;
    const int head = ntp >> 1, sub = ntp & 1;
    const int kblk = l0q >> 1, mtk = l0q & 1;

    const unsigned* rb = rfbuf + (size_t)rest * 1536 + ((proj * 2) * 64 + lane) * 4;
    uint4 q0 = *(const uint4*)(rb);
    uint4 q1 = *(const uint4*)(rb + 256);
    S8U r0, r1;
    r0.u[0] = make_uint2(q0.x, q0.y); r0.u[1] = make_uint2(q0.z, q0.w);
    r1.u[0] = make_uint2(q1.x, q1.y); r1.u[1] = make_uint2(q1.z, q1.w);

    const ushort* wp = wqkvF + ((size_t)(proj * 32 + ntp) * 4) * 256;  // [kc2][h][l31][8]
    short8 wf0 = *(const short8*)(wp + (size_t)h * 256 + l31 * 8);
    short8 wf1 = *(const short8*)(wp + (size_t)(2 + h) * 256 + l31 * 8);
    float16v c = {};
    if (proj < 2) {   // A=w (lane=ch), B=res (lane=row) -> C col=row
        c = __builtin_amdgcn_mfma_f32_32x32x16_bf16(wf0, r0.v, c, 0, 0, 0);
        c = __builtin_amdgcn_mfma_f32_32x32x16_bf16(wf1, r1.v, c, 0, 0, 0);
    } else {          // A=res (lane=row), B=w (lane=ch) -> C col=ch
        c = __builtin_amdgcn_mfma_f32_32x32x16_bf16(r0.v, wf0, c, 0, 0, 0);
        c = __builtin_amdgcn_mfma_f32_32x32x16_bf16(r1.v, wf1, c, 0, 0, 0);
    }
    unsigned pkc[8];
#pragma unroll
    for (int j = 0; j < 8; j++) pkc[j] = pk2(c[2 * j], c[2 * j + 1]);

    if (proj == 0) {
        ushort* base = qtile + (((size_t)(b * NH + head) * 64 + l0q)) * 2048;
#pragma unroll
        for (int cc = 0; cc < 2; cc++)
            *(short8*)(base + (sub * 2 + cc) * 512 + h * 256 + l31 * 8) =
                pk_frag(pkc, cc);
    } else if (proj == 1) {
        ushort* base = ktile + ((size_t)(b * NH + head) * 32 + kblk) * 4096 + mtk * 2048;
#pragma unroll
        for (int cc = 0; cc < 2; cc++)
            *(short8*)(base + (sub * 2 + cc) * 512 + h * 256 + l31 * 8) =
                pk_frag(pkc, cc);
    } else {
        ushort* base = vtile + ((size_t)(b * NH + head) * 32 + kblk) * 4096 + sub * 2048;
#pragma unroll
        for (int cc = 0; cc < 2; cc++)
            *(short8*)(base + (mtk * 2 + cc) * 512 + h * 256 + l31 * 8) =
                pk_frag(pkc, cc);
    }
}

// ---------------------------------------------------------------------------
// flash8 v9: 1 q-tile/wave (v4 geometry, grid 1024) + 2-stage S pipeline.
// Persistent VGPR = qf 16 + O/La 48 + sS[2] 64 = 128 (v8's spill came from
// 2 q-tiles: 256 persistent). Body: issue loads -> QK(it+1) [operands in
// LDS since last barrier] -> exp(it) [independent of QK(it+1), issues while
// QK executes in the MFMA pipe] -> PV(it) -> park-late -> barrier. K staged
// 2 ahead (read kb[(it+1)&1], park K(it+2)->kb[it&1]); V 1 ahead.
// ---------------------------------------------------------------------------
__global__ __launch_bounds__(256, 2) void flash8(const ushort* __restrict__ qtile,
                                                 const ushort* __restrict__ ktile,
                                                 const ushort* __restrict__ vtile,
                                                 ushort* __restrict__ Opart,
                                                 float* __restrict__ lbuf) {
    __shared__ ushort kb[2][4096];           // 16 KB
    __shared__ ushort vb[2][4096];           // 16 KB
    const int t = threadIdx.x;
    const int wave = t >> 6, lane = t & 63;
    const int l31 = lane & 31, h = lane >> 5;
    const int d = blockIdx.x;                      // 1024 blocks
    const int logical = (d & 7) * 128 + (d >> 3);  // XCD x owns bh [4x,4x+4)
    const int bh = logical >> 5;
    const int inner = logical & 31;
    const int ksp = inner >> 4;
    const int qt = (inner & 15) * 4 + wave;        // 4 waves share the K/V stream
    const int fo = h * 256 + l31 * 8;
    const int so = t * 8;                          // 16B per thread staging slot

    const ushort* qtb = qtile + ((size_t)bh * 64 + qt) * 2048;
    short8 qf[4];
#pragma unroll
    for (int kc = 0; kc < 4; kc++) qf[kc] = *(const short8*)(qtb + kc * 512 + fo);

    const ushort* ktb = ktile + (size_t)bh * 32 * 4096;
    const ushort* vtb = vtile + (size_t)bh * 32 * 4096;
    const int k0 = ksp * 16;

    // prologue A: stage K(0)->kb[0], V(0)->vb[0]
    {
        const ushort* ks = ktb + (size_t)k0 * 4096;
        const ushort* vs = vtb + (size_t)k0 * 4096;
        short8 a0 = *(const short8*)(ks + so);
        short8 a1 = *(const short8*)(ks + 2048 + so);
        short8 b0 = *(const short8*)(vs + so);
        short8 b1 = *(const short8*)(vs + 2048 + so);
        *(short8*)(kb[0] + so) = a0; *(short8*)(kb[0] + 2048 + so) = a1;
        *(short8*)(vb[0] + so) = b0; *(short8*)(vb[0] + 2048 + so) = b1;
    }
    __syncthreads();

    S8U ones;
    ones.u[0] = make_uint2(0x3F803F80u, 0x3F803F80u);
    ones.u[1] = make_uint2(0x3F803F80u, 0x3F803F80u);

    // prologue B: QK(0) -> sS[0]; park K(1)->kb[1]
    float16v sS[2][2];
    {
        short8 ka0, ka1;
        {
            const ushort* ks = ktb + (size_t)(k0 + 1) * 4096;
            ka0 = *(const short8*)(ks + so);
            ka1 = *(const short8*)(ks + 2048 + so);
        }
        short8 kf[2][4];
#pragma unroll
        for (int mt = 0; mt < 2; mt++)
#pragma unroll
            for (int kc = 0; kc < 4; kc++)
                kf[mt][kc] = *(const short8*)(kb[0] + mt * 2048 + kc * 512 + fo);
        sS[0][0] = (float16v){};
        sS[0][1] = (float16v){};
#pragma unroll
        for (int kc = 0; kc < 4; kc++) {
            sS[0][0] = __builtin_amdgcn_mfma_f32_32x32x16_bf16(kf[0][kc], qf[kc], sS[0][0], 0, 0, 0);
            sS[0][1] = __builtin_amdgcn_mfma_f32_32x32x16_bf16(kf[1][kc], qf[kc], sS[0][1], 0, 0, 0);
        }
        *(short8*)(kb[1] + so) = ka0; *(short8*)(kb[1] + 2048 + so) = ka1;
    }
    __syncthreads();

    float16v O0 = {}, O1 = {}, La = {};

#pragma unroll
    for (int it = 0; it < 16; it++) {
        const int pc = it & 1, pn = pc ^ 1;

        // issue-early: K(it+2), V(it+1) global loads
        short8 ka0, ka1, va0, va1;
        if (it < 14) {
            const ushort* ks = ktb + (size_t)(k0 + it + 2) * 4096;
            ka0 = *(const short8*)(ks + so);
            ka1 = *(const short8*)(ks + 2048 + so);
        }
        if (it < 15) {
            const ushort* vs = vtb + (size_t)(k0 + it + 1) * 4096;
            va0 = *(const short8*)(vs + so);
            va1 = *(const short8*)(vs + 2048 + so);
        }

        // QK(it+1) from kb[pn] — before exp(it): exp issues in its shadow
        if (it < 15) {
            short8 kf[2][4];
#pragma unroll
            for (int mt = 0; mt < 2; mt++)
#pragma unroll
                for (int kc = 0; kc < 4; kc++)
                    kf[mt][kc] = *(const short8*)(kb[pn] + mt * 2048 + kc * 512 + fo);
            sS[pn][0] = (float16v){};
            sS[pn][1] = (float16v){};
#pragma unroll
            for (int kc = 0; kc < 4; kc++) {
                sS[pn][0] = __builtin_amdgcn_mfma_f32_32x32x16_bf16(kf[0][kc], qf[kc], sS[pn][0], 0, 0, 0);
                sS[pn][1] = __builtin_amdgcn_mfma_f32_32x32x16_bf16(kf[1][kc], qf[kc], sS[pn][1], 0, 0, 0);
            }
        }

        // exp(it) from sS[pc] (completed last iter -> operand-ready)
        unsigned pk0[8], pk1[8];
#pragma unroll
        for (int j2 = 0; j2 < 8; j2++) {
            pk0[j2] = pk2(__builtin_amdgcn_exp2f(sS[pc][0][2 * j2]),
                          __builtin_amdgcn_exp2f(sS[pc][0][2 * j2 + 1]));
            pk1[j2] = pk2(__builtin_amdgcn_exp2f(sS[pc][1][2 * j2]),
                          __builtin_amdgcn_exp2f(sS[pc][1][2 * j2 + 1]));
        }

        // PV(it) from vb[pc]
        short8 vf[2][4];
#pragma unroll
        for (int mt = 0; mt < 2; mt++)
#pragma unroll
            for (int kc = 0; kc < 4; kc++)
                vf[mt][kc] = *(const short8*)(vb[pc] + mt * 2048 + kc * 512 + fo);
#pragma unroll
        for (int kc = 0; kc < 4; kc++) {
            const unsigned* pkm = (kc < 2) ? pk0 : pk1;
            short8 bf = pk_frag(pkm, kc & 1);
            La = __builtin_amdgcn_mfma_f32_32x32x16_bf16(ones.v, bf, La, 0, 0, 0);
            O0 = __builtin_amdgcn_mfma_f32_32x32x16_bf16(vf[0][kc], bf, O0, 0, 0, 0);
            O1 = __builtin_amdgcn_mfma_f32_32x32x16_bf16(vf[1][kc], bf, O1, 0, 0, 0);
        }

        // park-late (v6-verified ordering), then barrier
        if (it < 14) {
            *(short8*)(kb[pc] + so) = ka0; *(short8*)(kb[pc] + 2048 + so) = ka1;
        }
        if (it < 15) {
            *(short8*)(vb[pn] + so) = va0; *(short8*)(vb[pn] + 2048 + so) = va1;
            __syncthreads();
        }
    }

    // ---- epilogue: raw C-frag (pi-permuted d slots), b128 stores ----
    if (h == 0) lbuf[(size_t)ksp * 65536 + bh * 2048 + qt * 32 + l31] = La[0];
    ushort* ob = Opart + (size_t)ksp * 4194304 + ((size_t)bh * 64 + qt) * 2048;
#pragma unroll
    for (int mt = 0; mt < 2; mt++) {
        float16v Ov = mt ? O1 : O0;
        unsigned pkO[8];
#pragma unroll
        for (int j2 = 0; j2 < 8; j2++) pkO[j2] = pk2(Ov[2 * j2], Ov[2 * j2 + 1]);
#pragma unroll
        for (int cc = 0; cc < 2; cc++)
            *(short8*)(ob + ((mt * 2 + cc) * 2 + h) * 256 + l31 * 8) =
                pk_frag(pkO, cc);
    }
}

// ---------------------------------------------------------------------------
// back1: unchanged (verified round 1).
//   respart2[hq][rg][r][lane] fp32, 2 MB (aliases qtile; provably safe).
// ---------------------------------------------------------------------------
__global__ __launch_bounds__(256) void back1_kern(const ushort* __restrict__ Opart,
                                                  const float* __restrict__ lbuf,
                                                  const ushort* __restrict__ bF,
                                                  float* __restrict__ respart2) {
    __shared__ float red[4 * 16 * 64];       // 16 KB
    const int t = threadIdx.x, wave = t >> 6, lane = t & 63;
    const int l31 = lane & 31, h = lane >> 5;
    const int hq = blockIdx.x & 3, rg = blockIdx.x >> 2;
    const int b = rg >> 6, qt = rg & 63;
    const int hd = hq * 4 + wave, bh = b * NH + hd;

    float lb = lbuf[(size_t)bh * 2048 + qt * 32 + l31] +
               lbuf[(size_t)65536 + (size_t)bh * 2048 + qt * 32 + l31];
    float invl = 1.0f / lb;
    const ushort* ob0 = Opart + ((size_t)bh * 64 + qt) * 2048;
    const ushort* ob1 = ob0 + 4194304;

    float16v c = {};
#pragma unroll
    for (int kc = 0; kc < 4; kc++) {
        short8 o0 = *(const short8*)(ob0 + (kc * 2 + h) * 256 + l31 * 8);
        short8 o1 = *(const short8*)(ob1 + (kc * 2 + h) * 256 + l31 * 8);
        float av[8];
#pragma unroll
        for (int e = 0; e < 8; e++)
            av[e] = (ubf((ushort)o0[e]) + ubf((ushort)o1[e])) * invl;
        S8U bn;
        bn.u[0] = make_uint2(pk2(av[0], av[1]), pk2(av[2], av[3]));
        bn.u[1] = make_uint2(pk2(av[4], av[5]), pk2(av[6], av[7]));
        int kcg = hd * 4 + kc;                // global channel chunk 0..63
        short8 a = *(const short8*)(bF + ((size_t)((3 * 64 + kcg) * 2 + h) * 32 + l31) * 8);
        c = __builtin_amdgcn_mfma_f32_32x32x16_bf16(a, bn.v, c, 0, 0, 0);
    }
#pragma unroll
    for (int r = 0; r < 16; r++) red[wave * 1024 + r * 64 + lane] = c[r];
    __syncthreads();
#pragma unroll
    for (int i = 0; i < 4; i++) {
        int e = i * 256 + t;
        respart2[((size_t)hq * 128 + rg) * 1024 + e] =
            (red[e] + red[1024 + e]) + (red[2048 + e] + red[3072 + e]);
    }
}

// ---------------------------------------------------------------------------
// back2: unchanged (verified round 1).
// ---------------------------------------------------------------------------
__global__ __launch_bounds__(256) void back2_kern(const float* __restrict__ respart2,
                                                  const ushort* __restrict__ wobF,
                                                  float* __restrict__ out) {
    const int t = threadIdx.x, wave = t >> 6, lane = t & 63;
    const int l31 = lane & 31, h = lane >> 5;
    const int ng = blockIdx.x & 7, rg = blockIdx.x >> 3;

    float cf[16];
#pragma unroll
    for (int r = 0; r < 16; r++) {
        const float* pp = respart2 + r * 64 + lane;
        cf[r] = (pp[(size_t)rg * 1024] + pp[(size_t)(128 + rg) * 1024]) +
                (pp[(size_t)(256 + rg) * 1024] + pp[(size_t)(384 + rg) * 1024]);
    }
    unsigned pkr[8];
#pragma unroll
    for (int j = 0; j < 8; j++) pkr[j] = pk2(cf[2 * j], cf[2 * j + 1]);
    short8 a0 = pk_frag(pkr, 0);
    short8 a1 = pk_frag(pkr, 1);

    int nt = ng * 4 + wave;
    const ushort* wp = wobF + (size_t)nt * 1024;   // [kc2][h][l31][8]
    short8 wf0 = *(const short8*)(wp + (size_t)h * 256 + l31 * 8);
    short8 wf1 = *(const short8*)(wp + (size_t)(2 + h) * 256 + l31 * 8);
    float16v co = {};
    co = __builtin_amdgcn_mfma_f32_32x32x16_bf16(a0, wf0, co, 0, 0, 0);
    co = __builtin_amdgcn_mfma_f32_32x32x16_bf16(a1, wf1, co, 0, 0, 0);
#pragma unroll
    for (int r = 0; r < 16; r++) {
        int row = rg * 32 + crow(r, h);
        out[(size_t)row * CD + nt * 32 + l31] = co[r];
    }
}

// ---------------------------------------------------------------------------
extern "C" void kernel_launch(void* const* d_in, const int* in_sizes, int n_in,
                              void* d_out, int out_size, void* d_ws, size_t ws_size,
                              hipStream_t stream) {
    const float* x  = (const float*)d_in[0];
    const float* bq = (const float*)d_in[1];
    const float* pq = (const float*)d_in[2];
    const float* aq = (const float*)d_in[3];
    const float* bk = (const float*)d_in[4];
    const float* pk = (const float*)d_in[5];
    const float* ak = (const float*)d_in[6];
    const float* bv = (const float*)d_in[7];
    const float* pv = (const float*)d_in[8];
    const float* av = (const float*)d_in[9];
    const float* bo = (const float*)d_in[10];
    const float* po = (const float*)d_in[11];
    const float* ao = (const float*)d_in[12];

    char* ws = (char*)d_ws;
    ushort* bF      = (ushort*)(ws + 0);          // 256 KB
    ushort* wqkvF   = (ushort*)(ws + 262144);     // 192 KB
    ushort* wobF    = (ushort*)(ws + 458752);     //  64 KB
    ushort* qtile   = (ushort*)(ws + 524288);     //   8 MB
    ushort* ktile   = (ushort*)(ws + 8912896);    //   8 MB
    ushort* vtile   = (ushort*)(ws + 17301504);   //   8 MB
    ushort* Opart   = (ushort*)(ws + 25690112);   //  16 MB (2 ksp x 8 MB, bf16)
    float*  lbuf    = (float*)(ws + 42467328);    // 512 KB
    float*  respart = (float*)(ws + 42991616);    //   6 MB dedicated -> ~49 MB total
    float*  respart2= (float*)(ws + 524288);      //   2 MB alias of qtile (safe:
                                                  //   qtile fully rewritten each iter)
    unsigned* rfbuf = (unsigned*)(ws + 25690112); // 768 KB alias of Opart (safe:
                                                  //   rp writes + qkv reads BEFORE
                                                  //   flash8 overwrites Opart)

    prep_kern<<<128, 256, 0, stream>>>(bq, bk, bv, bo, pq, aq, pk, ak, pv, av,
                                       po, ao, bF, wqkvF, wobF);
    res_part_kern<<<512, 256, 0, stream>>>(x, bF, respart);
    rp_kern<<<192, 256, 0, stream>>>(respart, rfbuf);
    qkv_kern<<<3072, 256, 0, stream>>>(rfbuf, wqkvF, qtile, ktile, vtile);
    flash8<<<BSZ * NH * 32, 256, 0, stream>>>(qtile, ktile, vtile, Opart, lbuf);
    back1_kern<<<512, 256, 0, stream>>>(Opart, lbuf, bF, respart2);
    back2_kern<<<1024, 256, 0, stream>>>(respart2, wobF, (float*)d_out);
}

// Round 20
// 151.681 us; speedup vs baseline: 1.0155x; 1.0155x over previous
//
#include <hip/hip_runtime.h>
#include <hip/hip_bf16.h>
#include <cstdint>
#include <cstddef>

#define NH   16
#define HD   64
#define CD   1024
#define HARM 32
#define BSZ  2
#define LSEQ 2048
#define NROW (BSZ*LSEQ)   // 4096

typedef __attribute__((ext_vector_type(8))) short short8;     // 8 bf16 (A/B frag)
typedef __attribute__((ext_vector_type(16))) float float16v;  // 32x32 C frag

__device__ inline ushort bf16u(float f) {
    __hip_bfloat16 h = __float2bfloat16(f);
    return *(ushort*)&h;
}
__device__ inline float ubf(ushort u) {
    return __uint_as_float((unsigned)u << 16);
}
__device__ inline unsigned pk2(float a, float b) {
    return (unsigned)bf16u(a) | ((unsigned)bf16u(b) << 16);
}
// C-frag register r -> row offset within 32-row tile
__device__ inline int crow(int r, int half) { return (r & 3) + 8 * (r >> 2) + 4 * half; }

union S8U { short8 v; uint2 u[2]; };

// pi-permuted operand frag: raw packed C-frag regs for 16-k chunk cc.
// Slot (h,e) holds k = (e&3)+8*(e>>2)+4h (the involution pi). Valid as an
// MFMA A/B operand whenever the OTHER operand carries the same pi in its
// k-slots (pre-baked into weight tiles at prep, or raw C-frag on both sides).
__device__ inline short8 pk_frag(const unsigned* pk, int cc) {
    S8U o;
    o.u[0] = make_uint2(pk[4 * cc + 0], pk[4 * cc + 1]);
    o.u[1] = make_uint2(pk[4 * cc + 2], pk[4 * cc + 3]);
    return o.v;
}

// ---------------------------------------------------------------------------
// prep: fragment-tile all weights.
//   bF proj 0..2: STANDARD slot order (pairs with x-chunks in resrp).
//   bF proj 3, wqkvF, wobF: pi-permuted slot order (pair with raw C-frags).
// ---------------------------------------------------------------------------
__global__ void prep_kern(const float* __restrict__ bq, const float* __restrict__ bk,
                          const float* __restrict__ bv, const float* __restrict__ bo,
                          const float* __restrict__ pq, const float* __restrict__ aq,
                          const float* __restrict__ pk, const float* __restrict__ ak,
                          const float* __restrict__ pv, const float* __restrict__ av,
                          const float* __restrict__ po, const float* __restrict__ ao,
                          ushort* __restrict__ bF, ushort* __restrict__ wqkvF,
                          ushort* __restrict__ wobF) {
    const float QSCALE = 0.125f * 1.44269504088896340736f;  // hd^-0.5 * log2e
    unsigned tid = blockIdx.x * 256 + threadIdx.x;
    if (tid < 16384) {                 // bF
        unsigned l31 = tid & 31, h = (tid >> 5) & 1, kc = (tid >> 6) & 63, proj = tid >> 12;
        const float* bp = (proj == 0) ? bq : (proj == 1) ? bk : (proj == 2) ? bv : bo;
        const float* s = bp + (size_t)l31 * CD + kc * 16;
        // proj 3 permuted: elements {4h..4h+3, 8+4h..8+4h+3}; else {8h..8h+7}
        unsigned o0 = (proj == 3) ? h * 4 : h * 8;
        unsigned o1 = o0 + ((proj == 3) ? 8 : 4);
        float4 f0 = *(const float4*)(s + o0), f1 = *(const float4*)(s + o1);
        S8U o;
        o.u[0] = make_uint2(pk2(f0.x, f0.y), pk2(f0.z, f0.w));
        o.u[1] = make_uint2(pk2(f1.x, f1.y), pk2(f1.z, f1.w));
        *(short8*)(bF + (size_t)tid * 8) = o.v;
        return;
    }
    if (tid < 28672) {                 // wqkvF (pi-permuted harmonic slots)
        unsigned i = tid - 16384;
        unsigned l31 = i & 31, h = (i >> 5) & 1, kc2 = (i >> 6) & 1;
        unsigned ntp = (i >> 7) & 31, proj = i >> 12;
        const float* ph = (proj == 0) ? pq : (proj == 1) ? pk : pv;
        const float* am = (proj == 0) ? aq : (proj == 1) ? ak : av;
        float sc = (proj == 0) ? QSCALE : 1.0f;
        size_t s = (size_t)(ntp * 32 + l31) * HARM + kc2 * 16 + h * 4;
        float4 p0 = *(const float4*)(ph + s), p1 = *(const float4*)(ph + s + 8);
        float4 a0 = *(const float4*)(am + s), a1 = *(const float4*)(am + s + 8);
        S8U o;
        o.u[0] = make_uint2(pk2(a0.x * cosf(p0.x) * sc, a0.y * cosf(p0.y) * sc),
                            pk2(a0.z * cosf(p0.z) * sc, a0.w * cosf(p0.w) * sc));
        o.u[1] = make_uint2(pk2(a1.x * cosf(p1.x) * sc, a1.y * cosf(p1.y) * sc),
                            pk2(a1.z * cosf(p1.z) * sc, a1.w * cosf(p1.w) * sc));
        *(short8*)(wqkvF + (size_t)i * 8) = o.v;
        return;
    }
    {                                  // wobF (pi-permuted harmonic slots)
        unsigned i = tid - 28672;      // 4096
        unsigned l31 = i & 31, h = (i >> 5) & 1, kc2 = (i >> 6) & 1, nt = i >> 7;
        size_t s = (size_t)(nt * 32 + l31) * HARM + kc2 * 16 + h * 4;
        float4 p0 = *(const float4*)(po + s), p1 = *(const float4*)(po + s + 8);
        float4 a0 = *(const float4*)(ao + s), a1 = *(const float4*)(ao + s + 8);
        S8U o;
        o.u[0] = make_uint2(pk2(a0.x * cosf(p0.x), a0.y * cosf(p0.y)),
                            pk2(a0.z * cosf(p0.z), a0.w * cosf(p0.w)));
        o.u[1] = make_uint2(pk2(a1.x * cosf(p1.x), a1.y * cosf(p1.y)),
                            pk2(a1.z * cosf(p1.z), a1.w * cosf(p1.w)));
        *(short8*)(wobF + (size_t)i * 8) = o.v;
    }
}

// ---------------------------------------------------------------------------
// resrp (fused res_part + rp): one block per rg (grid 128, 8 waves).
// Stages full 32x1024 x-tile (64 KB, same per-256-col swizzle), each wave
// MFMA-accumulates 8 of 64 k-chunks (kcg = wave*8+i, same bF indexing),
// then 8-way cross-wave reduce + pk2 pack writes rfbuf DIRECTLY.
// Eliminates the 6 MB respart write + 6 MB rp re-read + one launch.
// red aliases xs (xs dead after MFMA phase) -> static LDS stays 64 KB.
// rfbuf[rest][p][cc][lane][q]: word (p, j=4cc+q, lane) =
//   pk2(sum_r=2j, sum_r=2j+1) — same layout qkv v4 consumes.
// ---------------------------------------------------------------------------
__global__ __launch_bounds__(512) void resrp_kern(const float* __restrict__ x,
                                                  const ushort* __restrict__ bF,
                                                  unsigned* __restrict__ rfbuf) {
    __shared__ ushort xs[4][8192];           // 64 KB  [kseg][row*256+chunk*8+sub*4]
    float* red = (float*)xs;                 // aliases xs: 8 waves x 1024 = 32 KB
    const int t = threadIdx.x, wave = t >> 6, lane = t & 63;
    const int l31 = lane & 31, h = lane >> 5;
    const int rest = blockIdx.x;             // 0..127
    const int n0 = rest * 32;

    // stage all 4 ksegs: 16 coalesced float4 loads per thread
#pragma unroll
    for (int i = 0; i < 16; i++) {
        int idx = i * 512 + t;               // 0..8191 float4 slots
        int row = idx >> 8, c4g = idx & 255;
        int kseg = c4g >> 6, c4 = c4g & 63;
        float4 v = *(const float4*)(x + (size_t)(n0 + row) * CD + kseg * 256 + c4 * 4);
        int chunk = (c4 >> 1) ^ (row & 15), sub = c4 & 1;
        *(ushort4*)(&xs[kseg][row * 256 + chunk * 8 + sub * 4]) =
            make_ushort4(bf16u(v.x), bf16u(v.y), bf16u(v.z), bf16u(v.w));
    }
    __syncthreads();

    float16v resC[3] = {};
#pragma unroll
    for (int i = 0; i < 8; i++) {
        int kcg = wave * 8 + i;              // 0..63
        int kseg = kcg >> 4, m = kcg & 15;
        int c = m * 2 + h;
        short8 bx = *(const short8*)(&xs[kseg][l31 * 256 + ((c ^ (l31 & 15)) * 8)]);
#pragma unroll
        for (int p = 0; p < 3; p++) {
            short8 a = *(const short8*)(bF + ((size_t)((p * 64 + kcg) * 2 + h) * 32 + l31) * 8);
            resC[p] = __builtin_amdgcn_mfma_f32_32x32x16_bf16(a, bx, resC[p], 0, 0, 0);
        }
    }

    unsigned* ob = rfbuf + (size_t)rest * 1536;
    for (int p = 0; p < 3; p++) {
        __syncthreads();                     // xs/red free (prev phase done)
#pragma unroll
        for (int r = 0; r < 16; r++) red[wave * 1024 + r * 64 + lane] = resC[p][r];
        __syncthreads();
        if (t < 128) {
            int cc = t >> 6, ln = t & 63;
            unsigned w[4];
#pragma unroll
            for (int q = 0; q < 4; q++) {
                int j = cc * 4 + q;
                float va = 0.0f, vb2 = 0.0f;
#pragma unroll
                for (int wv = 0; wv < 8; wv++) {
                    va  += red[wv * 1024 + (2 * j) * 64 + ln];
                    vb2 += red[wv * 1024 + (2 * j + 1) * 64 + ln];
                }
                w[q] = pk2(va, vb2);
            }
            *(uint4*)(ob + ((p * 2 + cc) * 64 + ln) * 4) =
                make_uint4(w[0], w[1], w[2], w[3]);
        }
    }
}

// ---------------------------------------------------------------------------
// qkv v4: pure phase-2 (verified round 8).
// ---------------------------------------------------------------------------
__global__ __launch_bounds__(256) void qkv_kern(const unsigned* __restrict__ rfbuf,
                                                const ushort* __restrict__ wqkvF,
                                                ushort* __restrict__ qtile,
                                                ushort* __restrict__ ktile,
                                                ushort* __restrict__ vtile) {
    const int t = threadIdx.x, wave = t >> 6, lane = t & 63;
    const int l31 = lane & 31, h = lane >> 5;
    const int ntg = blockIdx.x % 24, rest = blockIdx.x / 24;
    const int b = rest >> 6, l0q = rest & 63;
    const int nt = ntg * 4 + wave;               // 0..95
    const int proj = nt >> 5, ntp = nt & 31;
    const int head = ntp >> 1, sub = ntp & 1;
    const int kblk = l0q >> 1, mtk = l0q & 1;

    const unsigned* rb = rfbuf + (size_t)rest * 1536 + ((proj * 2) * 64 + lane) * 4;
    uint4 q0 = *(const uint4*)(rb);
    uint4 q1 = *(const uint4*)(rb + 256);
    S8U r0, r1;
    r0.u[0] = make_uint2(q0.x, q0.y); r0.u[1] = make_uint2(q0.z, q0.w);
    r1.u[0] = make_uint2(q1.x, q1.y); r1.u[1] = make_uint2(q1.z, q1.w);

    const ushort* wp = wqkvF + ((size_t)(proj * 32 + ntp) * 4) * 256;  // [kc2][h][l31][8]
    short8 wf0 = *(const short8*)(wp + (size_t)h * 256 + l31 * 8);
    short8 wf1 = *(const short8*)(wp + (size_t)(2 + h) * 256 + l31 * 8);
    float16v c = {};
    if (proj < 2) {   // A=w (lane=ch), B=res (lane=row) -> C col=row
        c = __builtin_amdgcn_mfma_f32_32x32x16_bf16(wf0, r0.v, c, 0, 0, 0);
        c = __builtin_amdgcn_mfma_f32_32x32x16_bf16(wf1, r1.v, c, 0, 0, 0);
    } else {          // A=res (lane=row), B=w (lane=ch) -> C col=ch
        c = __builtin_amdgcn_mfma_f32_32x32x16_bf16(r0.v, wf0, c, 0, 0, 0);
        c = __builtin_amdgcn_mfma_f32_32x32x16_bf16(r1.v, wf1, c, 0, 0, 0);
    }
    unsigned pkc[8];
#pragma unroll
    for (int j = 0; j < 8; j++) pkc[j] = pk2(c[2 * j], c[2 * j + 1]);

    if (proj == 0) {
        ushort* base = qtile + (((size_t)(b * NH + head) * 64 + l0q)) * 2048;
#pragma unroll
        for (int cc = 0; cc < 2; cc++)
            *(short8*)(base + (sub * 2 + cc) * 512 + h * 256 + l31 * 8) =
                pk_frag(pkc, cc);
    } else if (proj == 1) {
        ushort* base = ktile + ((size_t)(b * NH + head) * 32 + kblk) * 4096 + mtk * 2048;
#pragma unroll
        for (int cc = 0; cc < 2; cc++)
            *(short8*)(base + (sub * 2 + cc) * 512 + h * 256 + l31 * 8) =
                pk_frag(pkc, cc);
    } else {
        ushort* base = vtile + ((size_t)(b * NH + head) * 32 + kblk) * 4096 + sub * 2048;
#pragma unroll
        for (int cc = 0; cc < 2; cc++)
            *(short8*)(base + (mtk * 2 + cc) * 512 + h * 256 + l31 * 8) =
                pk_frag(pkc, cc);
    }
}

// ---------------------------------------------------------------------------
// flash8 v6 (round-11 verified best; v9 pipeline nulled at 46.8 vs ~43-45):
// 2 q-tiles per wave; 40 MFMA per iter per wave against 16 LDS reads and
// one barrier; park-late ordering. Grid 512 (32 bh x 2 ksp x 8 qt-groups).
// ---------------------------------------------------------------------------
__global__ __launch_bounds__(256, 2) void flash8(const ushort* __restrict__ qtile,
                                                 const ushort* __restrict__ ktile,
                                                 const ushort* __restrict__ vtile,
                                                 ushort* __restrict__ Opart,
                                                 float* __restrict__ lbuf) {
    __shared__ ushort kb[2][4096];           // 16 KB
    __shared__ ushort vb[2][4096];           // 16 KB
    const int t = threadIdx.x;
    const int wave = t >> 6, lane = t & 63;
    const int l31 = lane & 31, h = lane >> 5;
    const int d = blockIdx.x;                      // 512 blocks
    const int logical = (d & 7) * 64 + (d >> 3);   // XCD x owns bh [4x,4x+4)
    const int bh = logical >> 4;
    const int inner = logical & 15;
    const int ksp = inner >> 3;
    const int qtg = inner & 7;
    const int qt0 = qtg * 8 + wave * 2;            // wave owns qt0, qt0+1
    const int fo = h * 256 + l31 * 8;
    const int so = t * 8;                          // 16B per thread staging slot

    const ushort* qtb = qtile + ((size_t)bh * 64 + qt0) * 2048;
    short8 qfa[4], qfb[4];
#pragma unroll
    for (int kc = 0; kc < 4; kc++) {
        qfa[kc] = *(const short8*)(qtb + kc * 512 + fo);
        qfb[kc] = *(const short8*)(qtb + 2048 + kc * 512 + fo);
    }

    const ushort* ktb = ktile + (size_t)bh * 32 * 4096;
    const ushort* vtb = vtile + (size_t)bh * 32 * 4096;
    const int k0 = ksp * 16;

    // prologue: stage kblk k0 into buffer 0
    {
        const ushort* ks = ktb + (size_t)k0 * 4096;
        const ushort* vs = vtb + (size_t)k0 * 4096;
        short8 a0 = *(const short8*)(ks + so);
        short8 a1 = *(const short8*)(ks + 2048 + so);
        short8 b0 = *(const short8*)(vs + so);
        short8 b1 = *(const short8*)(vs + 2048 + so);
        *(short8*)(kb[0] + so) = a0; *(short8*)(kb[0] + 2048 + so) = a1;
        *(short8*)(vb[0] + so) = b0; *(short8*)(vb[0] + 2048 + so) = b1;
    }
    __syncthreads();

    S8U ones;
    ones.u[0] = make_uint2(0x3F803F80u, 0x3F803F80u);
    ones.u[1] = make_uint2(0x3F803F80u, 0x3F803F80u);

    float16v O0a = {}, O1a = {}, Laa = {};
    float16v O0b = {}, O1b = {}, Lab = {};

#pragma unroll
    for (int it = 0; it < 16; it++) {
        const int cur = it & 1, nxt = cur ^ 1;

        // T14 issue-early: next tile's global loads start now, land during compute
        short8 a0, a1, b0, b1;
        if (it < 15) {
            const ushort* ks = ktb + (size_t)(k0 + it + 1) * 4096;
            const ushort* vs = vtb + (size_t)(k0 + it + 1) * 4096;
            a0 = *(const short8*)(ks + so);
            a1 = *(const short8*)(ks + 2048 + so);
            b0 = *(const short8*)(vs + so);
            b1 = *(const short8*)(vs + 2048 + so);
        }

        short8 kf[2][4];
#pragma unroll
        for (int mt = 0; mt < 2; mt++)
#pragma unroll
            for (int kc = 0; kc < 4; kc++)
                kf[mt][kc] = *(const short8*)(kb[cur] + mt * 2048 + kc * 512 + fo);
        float16v s0a = {}, s1a = {}, s0b = {}, s1b = {};
#pragma unroll
        for (int kc = 0; kc < 4; kc++) {
            s0a = __builtin_amdgcn_mfma_f32_32x32x16_bf16(kf[0][kc], qfa[kc], s0a, 0, 0, 0);
            s1a = __builtin_amdgcn_mfma_f32_32x32x16_bf16(kf[1][kc], qfa[kc], s1a, 0, 0, 0);
            s0b = __builtin_amdgcn_mfma_f32_32x32x16_bf16(kf[0][kc], qfb[kc], s0b, 0, 0, 0);
            s1b = __builtin_amdgcn_mfma_f32_32x32x16_bf16(kf[1][kc], qfb[kc], s1b, 0, 0, 0);
        }
        short8 vf[2][4];
#pragma unroll
        for (int mt = 0; mt < 2; mt++)
#pragma unroll
            for (int kc = 0; kc < 4; kc++)
                vf[mt][kc] = *(const short8*)(vb[cur] + mt * 2048 + kc * 512 + fo);

        unsigned pk0a[8], pk1a[8], pk0b[8], pk1b[8];
#pragma unroll
        for (int j2 = 0; j2 < 8; j2++) {
            pk0a[j2] = pk2(__builtin_amdgcn_exp2f(s0a[2 * j2]),
                           __builtin_amdgcn_exp2f(s0a[2 * j2 + 1]));
            pk1a[j2] = pk2(__builtin_amdgcn_exp2f(s1a[2 * j2]),
                           __builtin_amdgcn_exp2f(s1a[2 * j2 + 1]));
            pk0b[j2] = pk2(__builtin_amdgcn_exp2f(s0b[2 * j2]),
                           __builtin_amdgcn_exp2f(s0b[2 * j2 + 1]));
            pk1b[j2] = pk2(__builtin_amdgcn_exp2f(s1b[2 * j2]),
                           __builtin_amdgcn_exp2f(s1b[2 * j2 + 1]));
        }
#pragma unroll
        for (int kc = 0; kc < 4; kc++) {
            const unsigned* pma = (kc < 2) ? pk0a : pk1a;
            const unsigned* pmb = (kc < 2) ? pk0b : pk1b;
            short8 bfa = pk_frag(pma, kc & 1);
            short8 bfb = pk_frag(pmb, kc & 1);
            Laa = __builtin_amdgcn_mfma_f32_32x32x16_bf16(ones.v, bfa, Laa, 0, 0, 0);
            O0a = __builtin_amdgcn_mfma_f32_32x32x16_bf16(vf[0][kc], bfa, O0a, 0, 0, 0);
            O1a = __builtin_amdgcn_mfma_f32_32x32x16_bf16(vf[1][kc], bfa, O1a, 0, 0, 0);
            Lab = __builtin_amdgcn_mfma_f32_32x32x16_bf16(ones.v, bfb, Lab, 0, 0, 0);
            O0b = __builtin_amdgcn_mfma_f32_32x32x16_bf16(vf[0][kc], bfb, O0b, 0, 0, 0);
            O1b = __builtin_amdgcn_mfma_f32_32x32x16_bf16(vf[1][kc], bfb, O1b, 0, 0, 0);
        }

        // write-late: park next tile in the other buffer, then barrier
        if (it < 15) {
            *(short8*)(kb[nxt] + so) = a0; *(short8*)(kb[nxt] + 2048 + so) = a1;
            *(short8*)(vb[nxt] + so) = b0; *(short8*)(vb[nxt] + 2048 + so) = b1;
        }
        __syncthreads();
    }

    // ---- epilogue: raw C-frag (pi-permuted d slots), b128 stores, 2 qt ----
    if (h == 0) {
        lbuf[(size_t)ksp * 65536 + bh * 2048 + qt0 * 32 + l31] = Laa[0];
        lbuf[(size_t)ksp * 65536 + bh * 2048 + (qt0 + 1) * 32 + l31] = Lab[0];
    }
#pragma unroll
    for (int j = 0; j < 2; j++) {
        ushort* ob = Opart + (size_t)ksp * 4194304 + ((size_t)bh * 64 + qt0 + j) * 2048;
#pragma unroll
        for (int mt = 0; mt < 2; mt++) {
            float16v Ov = j ? (mt ? O1b : O0b) : (mt ? O1a : O0a);
            unsigned pkO[8];
#pragma unroll
            for (int j2 = 0; j2 < 8; j2++) pkO[j2] = pk2(Ov[2 * j2], Ov[2 * j2 + 1]);
#pragma unroll
            for (int cc = 0; cc < 2; cc++)
                *(short8*)(ob + ((mt * 2 + cc) * 2 + h) * 256 + l31 * 8) =
                    pk_frag(pkO, cc);
        }
    }
}

// ---------------------------------------------------------------------------
// back1: unchanged (verified round 1).
//   respart2[hq][rg][r][lane] fp32, 2 MB (aliases qtile; provably safe).
// ---------------------------------------------------------------------------
__global__ __launch_bounds__(256) void back1_kern(const ushort* __restrict__ Opart,
                                                  const float* __restrict__ lbuf,
                                                  const ushort* __restrict__ bF,
                                                  float* __restrict__ respart2) {
    __shared__ float red[4 * 16 * 64];       // 16 KB
    const int t = threadIdx.x, wave = t >> 6, lane = t & 63;
    const int l31 = lane & 31, h = lane >> 5;
    const int hq = blockIdx.x & 3, rg = blockIdx.x >> 2;
    const int b = rg >> 6, qt = rg & 63;
    const int hd = hq * 4 + wave, bh = b * NH + hd;

    float lb = lbuf[(size_t)bh * 2048 + qt * 32 + l31] +
               lbuf[(size_t)65536 + (size_t)bh * 2048 + qt * 32 + l31];
    float invl = 1.0f / lb;
    const ushort* ob0 = Opart + ((size_t)bh * 64 + qt) * 2048;
    const ushort* ob1 = ob0 + 4194304;

    float16v c = {};
#pragma unroll
    for (int kc = 0; kc < 4; kc++) {
        short8 o0 = *(const short8*)(ob0 + (kc * 2 + h) * 256 + l31 * 8);
        short8 o1 = *(const short8*)(ob1 + (kc * 2 + h) * 256 + l31 * 8);
        float av[8];
#pragma unroll
        for (int e = 0; e < 8; e++)
            av[e] = (ubf((ushort)o0[e]) + ubf((ushort)o1[e])) * invl;
        S8U bn;
        bn.u[0] = make_uint2(pk2(av[0], av[1]), pk2(av[2], av[3]));
        bn.u[1] = make_uint2(pk2(av[4], av[5]), pk2(av[6], av[7]));
        int kcg = hd * 4 + kc;                // global channel chunk 0..63
        short8 a = *(const short8*)(bF + ((size_t)((3 * 64 + kcg) * 2 + h) * 32 + l31) * 8);
        c = __builtin_amdgcn_mfma_f32_32x32x16_bf16(a, bn.v, c, 0, 0, 0);
    }
#pragma unroll
    for (int r = 0; r < 16; r++) red[wave * 1024 + r * 64 + lane] = c[r];
    __syncthreads();
#pragma unroll
    for (int i = 0; i < 4; i++) {
        int e = i * 256 + t;
        respart2[((size_t)hq * 128 + rg) * 1024 + e] =
            (red[e] + red[1024 + e]) + (red[2048 + e] + red[3072 + e]);
    }
}

// ---------------------------------------------------------------------------
// back2: unchanged (verified round 1).
// ---------------------------------------------------------------------------
__global__ __launch_bounds__(256) void back2_kern(const float* __restrict__ respart2,
                                                  const ushort* __restrict__ wobF,
                                                  float* __restrict__ out) {
    const int t = threadIdx.x, wave = t >> 6, lane = t & 63;
    const int l31 = lane & 31, h = lane >> 5;
    const int ng = blockIdx.x & 7, rg = blockIdx.x >> 3;

    float cf[16];
#pragma unroll
    for (int r = 0; r < 16; r++) {
        const float* pp = respart2 + r * 64 + lane;
        cf[r] = (pp[(size_t)rg * 1024] + pp[(size_t)(128 + rg) * 1024]) +
                (pp[(size_t)(256 + rg) * 1024] + pp[(size_t)(384 + rg) * 1024]);
    }
    unsigned pkr[8];
#pragma unroll
    for (int j = 0; j < 8; j++) pkr[j] = pk2(cf[2 * j], cf[2 * j + 1]);
    short8 a0 = pk_frag(pkr, 0);
    short8 a1 = pk_frag(pkr, 1);

    int nt = ng * 4 + wave;
    const ushort* wp = wobF + (size_t)nt * 1024;   // [kc2][h][l31][8]
    short8 wf0 = *(const short8*)(wp + (size_t)h * 256 + l31 * 8);
    short8 wf1 = *(const short8*)(wp + (size_t)(2 + h) * 256 + l31 * 8);
    float16v co = {};
    co = __builtin_amdgcn_mfma_f32_32x32x16_bf16(a0, wf0, co, 0, 0, 0);
    co = __builtin_amdgcn_mfma_f32_32x32x16_bf16(a1, wf1, co, 0, 0, 0);
#pragma unroll
    for (int r = 0; r < 16; r++) {
        int row = rg * 32 + crow(r, h);
        out[(size_t)row * CD + nt * 32 + l31] = co[r];
    }
}

// ---------------------------------------------------------------------------
extern "C" void kernel_launch(void* const* d_in, const int* in_sizes, int n_in,
                              void* d_out, int out_size, void* d_ws, size_t ws_size,
                              hipStream_t stream) {
    const float* x  = (const float*)d_in[0];
    const float* bq = (const float*)d_in[1];
    const float* pq = (const float*)d_in[2];
    const float* aq = (const float*)d_in[3];
    const float* bk = (const float*)d_in[4];
    const float* pk = (const float*)d_in[5];
    const float* ak = (const float*)d_in[6];
    const float* bv = (const float*)d_in[7];
    const float* pv = (const float*)d_in[8];
    const float* av = (const float*)d_in[9];
    const float* bo = (const float*)d_in[10];
    const float* po = (const float*)d_in[11];
    const float* ao = (const float*)d_in[12];

    char* ws = (char*)d_ws;
    ushort* bF      = (ushort*)(ws + 0);          // 256 KB
    ushort* wqkvF   = (ushort*)(ws + 262144);     // 192 KB
    ushort* wobF    = (ushort*)(ws + 458752);     //  64 KB
    ushort* qtile   = (ushort*)(ws + 524288);     //   8 MB
    ushort* ktile   = (ushort*)(ws + 8912896);    //   8 MB
    ushort* vtile   = (ushort*)(ws + 17301504);   //   8 MB
    ushort* Opart   = (ushort*)(ws + 25690112);   //  16 MB (2 ksp x 8 MB, bf16)
    float*  lbuf    = (float*)(ws + 42467328);    // 512 KB
    float*  respart2= (float*)(ws + 524288);      //   2 MB alias of qtile (safe:
                                                  //   qtile fully rewritten each iter)
    unsigned* rfbuf = (unsigned*)(ws + 25690112); // 768 KB alias of Opart (safe:
                                                  //   resrp writes + qkv reads BEFORE
                                                  //   flash8 overwrites Opart)

    prep_kern<<<128, 256, 0, stream>>>(bq, bk, bv, bo, pq, aq, pk, ak, pv, av,
                                       po, ao, bF, wqkvF, wobF);
    resrp_kern<<<128, 512, 0, stream>>>(x, bF, rfbuf);
    qkv_kern<<<3072, 256, 0, stream>>>(rfbuf, wqkvF, qtile, ktile, vtile);
    flash8<<<512, 256, 0, stream>>>(qtile, ktile, vtile, Opart, lbuf);
    back1_kern<<<512, 256, 0, stream>>>(Opart, lbuf, bF, respart2);
    back2_kern<<<1024, 256, 0, stream>>>(respart2, wobF, (float*)d_out);
}

// Round 21
// 148.329 us; speedup vs baseline: 1.0384x; 1.0226x over previous
//
#include <hip/hip_runtime.h>
#include <hip/hip_bf16.h>
#include <cstdint>
#include <cstddef>

#define NH   16
#define HD   64
#define CD   1024
#define HARM 32
#define BSZ  2
#define LSEQ 2048
#define NROW (BSZ*LSEQ)   // 4096

typedef __attribute__((ext_vector_type(8))) short short8;     // 8 bf16 (A/B frag)
typedef __attribute__((ext_vector_type(16))) float float16v;  // 32x32 C frag

__device__ inline ushort bf16u(float f) {
    __hip_bfloat16 h = __float2bfloat16(f);
    return *(ushort*)&h;
}
__device__ inline float ubf(ushort u) {
    return __uint_as_float((unsigned)u << 16);
}
__device__ inline unsigned pk2(float a, float b) {
    return (unsigned)bf16u(a) | ((unsigned)bf16u(b) << 16);
}
// C-frag register r -> row offset within 32-row tile
__device__ inline int crow(int r, int half) { return (r & 3) + 8 * (r >> 2) + 4 * half; }

union S8U { short8 v; uint2 u[2]; };

// pi-permuted operand frag: raw packed C-frag regs for 16-k chunk cc.
// Slot (h,e) holds k = (e&3)+8*(e>>2)+4h (the involution pi). Valid as an
// MFMA A/B operand whenever the OTHER operand carries the same pi in its
// k-slots (pre-baked into weight tiles at prep, or raw C-frag on both sides).
__device__ inline short8 pk_frag(const unsigned* pk, int cc) {
    S8U o;
    o.u[0] = make_uint2(pk[4 * cc + 0], pk[4 * cc + 1]);
    o.u[1] = make_uint2(pk[4 * cc + 2], pk[4 * cc + 3]);
    return o.v;
}

// ---------------------------------------------------------------------------
// prep: fragment-tile all weights.
//   bF proj 0..2: STANDARD slot order (pairs with x-chunks in resrp).
//   bF proj 3, wqkvF, wobF: pi-permuted slot order (pair with raw C-frags).
// ---------------------------------------------------------------------------
__global__ void prep_kern(const float* __restrict__ bq, const float* __restrict__ bk,
                          const float* __restrict__ bv, const float* __restrict__ bo,
                          const float* __restrict__ pq, const float* __restrict__ aq,
                          const float* __restrict__ pk, const float* __restrict__ ak,
                          const float* __restrict__ pv, const float* __restrict__ av,
                          const float* __restrict__ po, const float* __restrict__ ao,
                          ushort* __restrict__ bF, ushort* __restrict__ wqkvF,
                          ushort* __restrict__ wobF) {
    const float QSCALE = 0.125f * 1.44269504088896340736f;  // hd^-0.5 * log2e
    unsigned tid = blockIdx.x * 256 + threadIdx.x;
    if (tid < 16384) {                 // bF
        unsigned l31 = tid & 31, h = (tid >> 5) & 1, kc = (tid >> 6) & 63, proj = tid >> 12;
        const float* bp = (proj == 0) ? bq : (proj == 1) ? bk : (proj == 2) ? bv : bo;
        const float* s = bp + (size_t)l31 * CD + kc * 16;
        // proj 3 permuted: elements {4h..4h+3, 8+4h..8+4h+3}; else {8h..8h+7}
        unsigned o0 = (proj == 3) ? h * 4 : h * 8;
        unsigned o1 = o0 + ((proj == 3) ? 8 : 4);
        float4 f0 = *(const float4*)(s + o0), f1 = *(const float4*)(s + o1);
        S8U o;
        o.u[0] = make_uint2(pk2(f0.x, f0.y), pk2(f0.z, f0.w));
        o.u[1] = make_uint2(pk2(f1.x, f1.y), pk2(f1.z, f1.w));
        *(short8*)(bF + (size_t)tid * 8) = o.v;
        return;
    }
    if (tid < 28672) {                 // wqkvF (pi-permuted harmonic slots)
        unsigned i = tid - 16384;
        unsigned l31 = i & 31, h = (i >> 5) & 1, kc2 = (i >> 6) & 1;
        unsigned ntp = (i >> 7) & 31, proj = i >> 12;
        const float* ph = (proj == 0) ? pq : (proj == 1) ? pk : pv;
        const float* am = (proj == 0) ? aq : (proj == 1) ? ak : av;
        float sc = (proj == 0) ? QSCALE : 1.0f;
        size_t s = (size_t)(ntp * 32 + l31) * HARM + kc2 * 16 + h * 4;
        float4 p0 = *(const float4*)(ph + s), p1 = *(const float4*)(ph + s + 8);
        float4 a0 = *(const float4*)(am + s), a1 = *(const float4*)(am + s + 8);
        S8U o;
        o.u[0] = make_uint2(pk2(a0.x * cosf(p0.x) * sc, a0.y * cosf(p0.y) * sc),
                            pk2(a0.z * cosf(p0.z) * sc, a0.w * cosf(p0.w) * sc));
        o.u[1] = make_uint2(pk2(a1.x * cosf(p1.x) * sc, a1.y * cosf(p1.y) * sc),
                            pk2(a1.z * cosf(p1.z) * sc, a1.w * cosf(p1.w) * sc));
        *(short8*)(wqkvF + (size_t)i * 8) = o.v;
        return;
    }
    {                                  // wobF (pi-permuted harmonic slots)
        unsigned i = tid - 28672;      // 4096
        unsigned l31 = i & 31, h = (i >> 5) & 1, kc2 = (i >> 6) & 1, nt = i >> 7;
        size_t s = (size_t)(nt * 32 + l31) * HARM + kc2 * 16 + h * 4;
        float4 p0 = *(const float4*)(po + s), p1 = *(const float4*)(po + s + 8);
        float4 a0 = *(const float4*)(ao + s), a1 = *(const float4*)(ao + s + 8);
        S8U o;
        o.u[0] = make_uint2(pk2(a0.x * cosf(p0.x), a0.y * cosf(p0.y)),
                            pk2(a0.z * cosf(p0.z), a0.w * cosf(p0.w)));
        o.u[1] = make_uint2(pk2(a1.x * cosf(p1.x), a1.y * cosf(p1.y)),
                            pk2(a1.z * cosf(p1.z), a1.w * cosf(p1.w)));
        *(short8*)(wobF + (size_t)i * 8) = o.v;
    }
}

// ---------------------------------------------------------------------------
// resrp (fused res_part + rp, verified round 20 — bit-identical absmax).
// ---------------------------------------------------------------------------
__global__ __launch_bounds__(512) void resrp_kern(const float* __restrict__ x,
                                                  const ushort* __restrict__ bF,
                                                  unsigned* __restrict__ rfbuf) {
    __shared__ ushort xs[4][8192];           // 64 KB  [kseg][row*256+chunk*8+sub*4]
    float* red = (float*)xs;                 // aliases xs: 8 waves x 1024 = 32 KB
    const int t = threadIdx.x, wave = t >> 6, lane = t & 63;
    const int l31 = lane & 31, h = lane >> 5;
    const int rest = blockIdx.x;             // 0..127
    const int n0 = rest * 32;

    // stage all 4 ksegs: 16 coalesced float4 loads per thread
#pragma unroll
    for (int i = 0; i < 16; i++) {
        int idx = i * 512 + t;               // 0..8191 float4 slots
        int row = idx >> 8, c4g = idx & 255;
        int kseg = c4g >> 6, c4 = c4g & 63;
        float4 v = *(const float4*)(x + (size_t)(n0 + row) * CD + kseg * 256 + c4 * 4);
        int chunk = (c4 >> 1) ^ (row & 15), sub = c4 & 1;
        *(ushort4*)(&xs[kseg][row * 256 + chunk * 8 + sub * 4]) =
            make_ushort4(bf16u(v.x), bf16u(v.y), bf16u(v.z), bf16u(v.w));
    }
    __syncthreads();

    float16v resC[3] = {};
#pragma unroll
    for (int i = 0; i < 8; i++) {
        int kcg = wave * 8 + i;              // 0..63
        int kseg = kcg >> 4, m = kcg & 15;
        int c = m * 2 + h;
        short8 bx = *(const short8*)(&xs[kseg][l31 * 256 + ((c ^ (l31 & 15)) * 8)]);
#pragma unroll
        for (int p = 0; p < 3; p++) {
            short8 a = *(const short8*)(bF + ((size_t)((p * 64 + kcg) * 2 + h) * 32 + l31) * 8);
            resC[p] = __builtin_amdgcn_mfma_f32_32x32x16_bf16(a, bx, resC[p], 0, 0, 0);
        }
    }

    unsigned* ob = rfbuf + (size_t)rest * 1536;
    for (int p = 0; p < 3; p++) {
        __syncthreads();                     // xs/red free (prev phase done)
#pragma unroll
        for (int r = 0; r < 16; r++) red[wave * 1024 + r * 64 + lane] = resC[p][r];
        __syncthreads();
        if (t < 128) {
            int cc = t >> 6, ln = t & 63;
            unsigned w[4];
#pragma unroll
            for (int q = 0; q < 4; q++) {
                int j = cc * 4 + q;
                float va = 0.0f, vb2 = 0.0f;
#pragma unroll
                for (int wv = 0; wv < 8; wv++) {
                    va  += red[wv * 1024 + (2 * j) * 64 + ln];
                    vb2 += red[wv * 1024 + (2 * j + 1) * 64 + ln];
                }
                w[q] = pk2(va, vb2);
            }
            *(uint4*)(ob + ((p * 2 + cc) * 64 + ln) * 4) =
                make_uint4(w[0], w[1], w[2], w[3]);
        }
    }
}

// ---------------------------------------------------------------------------
// qkv v4: pure phase-2 (verified round 8).
// ---------------------------------------------------------------------------
__global__ __launch_bounds__(256) void qkv_kern(const unsigned* __restrict__ rfbuf,
                                                const ushort* __restrict__ wqkvF,
                                                ushort* __restrict__ qtile,
                                                ushort* __restrict__ ktile,
                                                ushort* __restrict__ vtile) {
    const int t = threadIdx.x, wave = t >> 6, lane = t & 63;
    const int l31 = lane & 31, h = lane >> 5;
    const int ntg = blockIdx.x % 24, rest = blockIdx.x / 24;
    const int b = rest >> 6, l0q = rest & 63;
    const int nt = ntg * 4 + wave;               // 0..95
    const int proj = nt >> 5, ntp = nt & 31;
    const int head = ntp >> 1, sub = ntp & 1;
    const int kblk = l0q >> 1, mtk = l0q & 1;

    const unsigned* rb = rfbuf + (size_t)rest * 1536 + ((proj * 2) * 64 + lane) * 4;
    uint4 q0 = *(const uint4*)(rb);
    uint4 q1 = *(const uint4*)(rb + 256);
    S8U r0, r1;
    r0.u[0] = make_uint2(q0.x, q0.y); r0.u[1] = make_uint2(q0.z, q0.w);
    r1.u[0] = make_uint2(q1.x, q1.y); r1.u[1] = make_uint2(q1.z, q1.w);

    const ushort* wp = wqkvF + ((size_t)(proj * 32 + ntp) * 4) * 256;  // [kc2][h][l31][8]
    short8 wf0 = *(const short8*)(wp + (size_t)h * 256 + l31 * 8);
    short8 wf1 = *(const short8*)(wp + (size_t)(2 + h) * 256 + l31 * 8);
    float16v c = {};
    if (proj < 2) {   // A=w (lane=ch), B=res (lane=row) -> C col=row
        c = __builtin_amdgcn_mfma_f32_32x32x16_bf16(wf0, r0.v, c, 0, 0, 0);
        c = __builtin_amdgcn_mfma_f32_32x32x16_bf16(wf1, r1.v, c, 0, 0, 0);
    } else {          // A=res (lane=row), B=w (lane=ch) -> C col=ch
        c = __builtin_amdgcn_mfma_f32_32x32x16_bf16(r0.v, wf0, c, 0, 0, 0);
        c = __builtin_amdgcn_mfma_f32_32x32x16_bf16(r1.v, wf1, c, 0, 0, 0);
    }
    unsigned pkc[8];
#pragma unroll
    for (int j = 0; j < 8; j++) pkc[j] = pk2(c[2 * j], c[2 * j + 1]);

    if (proj == 0) {
        ushort* base = qtile + (((size_t)(b * NH + head) * 64 + l0q)) * 2048;
#pragma unroll
        for (int cc = 0; cc < 2; cc++)
            *(short8*)(base + (sub * 2 + cc) * 512 + h * 256 + l31 * 8) =
                pk_frag(pkc, cc);
    } else if (proj == 1) {
        ushort* base = ktile + ((size_t)(b * NH + head) * 32 + kblk) * 4096 + mtk * 2048;
#pragma unroll
        for (int cc = 0; cc < 2; cc++)
            *(short8*)(base + (sub * 2 + cc) * 512 + h * 256 + l31 * 8) =
                pk_frag(pkc, cc);
    } else {
        ushort* base = vtile + ((size_t)(b * NH + head) * 32 + kblk) * 4096 + sub * 2048;
#pragma unroll
        for (int cc = 0; cc < 2; cc++)
            *(short8*)(base + (mtk * 2 + cc) * 512 + h * 256 + l31 * 8) =
                pk_frag(pkc, cc);
    }
}

// ---------------------------------------------------------------------------
// flash8 v6 (round-11 verified best): 2 q-tiles per wave; 40 MFMA per iter
// per wave against 16 LDS reads and one barrier; park-late ordering.
// Grid 512 (32 bh x 2 ksp x 8 qt-groups); XCD swizzle.
// ---------------------------------------------------------------------------
__global__ __launch_bounds__(256, 2) void flash8(const ushort* __restrict__ qtile,
                                                 const ushort* __restrict__ ktile,
                                                 const ushort* __restrict__ vtile,
                                                 ushort* __restrict__ Opart,
                                                 float* __restrict__ lbuf) {
    __shared__ ushort kb[2][4096];           // 16 KB
    __shared__ ushort vb[2][4096];           // 16 KB
    const int t = threadIdx.x;
    const int wave = t >> 6, lane = t & 63;
    const int l31 = lane & 31, h = lane >> 5;
    const int d = blockIdx.x;                      // 512 blocks
    const int logical = (d & 7) * 64 + (d >> 3);   // XCD x owns bh [4x,4x+4)
    const int bh = logical >> 4;
    const int inner = logical & 15;
    const int ksp = inner >> 3;
    const int qtg = inner & 7;
    const int qt0 = qtg * 8 + wave * 2;            // wave owns qt0, qt0+1
    const int fo = h * 256 + l31 * 8;
    const int so = t * 8;                          // 16B per thread staging slot

    const ushort* qtb = qtile + ((size_t)bh * 64 + qt0) * 2048;
    short8 qfa[4], qfb[4];
#pragma unroll
    for (int kc = 0; kc < 4; kc++) {
        qfa[kc] = *(const short8*)(qtb + kc * 512 + fo);
        qfb[kc] = *(const short8*)(qtb + 2048 + kc * 512 + fo);
    }

    const ushort* ktb = ktile + (size_t)bh * 32 * 4096;
    const ushort* vtb = vtile + (size_t)bh * 32 * 4096;
    const int k0 = ksp * 16;

    // prologue: stage kblk k0 into buffer 0
    {
        const ushort* ks = ktb + (size_t)k0 * 4096;
        const ushort* vs = vtb + (size_t)k0 * 4096;
        short8 a0 = *(const short8*)(ks + so);
        short8 a1 = *(const short8*)(ks + 2048 + so);
        short8 b0 = *(const short8*)(vs + so);
        short8 b1 = *(const short8*)(vs + 2048 + so);
        *(short8*)(kb[0] + so) = a0; *(short8*)(kb[0] + 2048 + so) = a1;
        *(short8*)(vb[0] + so) = b0; *(short8*)(vb[0] + 2048 + so) = b1;
    }
    __syncthreads();

    S8U ones;
    ones.u[0] = make_uint2(0x3F803F80u, 0x3F803F80u);
    ones.u[1] = make_uint2(0x3F803F80u, 0x3F803F80u);

    float16v O0a = {}, O1a = {}, Laa = {};
    float16v O0b = {}, O1b = {}, Lab = {};

#pragma unroll
    for (int it = 0; it < 16; it++) {
        const int cur = it & 1, nxt = cur ^ 1;

        // T14 issue-early: next tile's global loads start now, land during compute
        short8 a0, a1, b0, b1;
        if (it < 15) {
            const ushort* ks = ktb + (size_t)(k0 + it + 1) * 4096;
            const ushort* vs = vtb + (size_t)(k0 + it + 1) * 4096;
            a0 = *(const short8*)(ks + so);
            a1 = *(const short8*)(ks + 2048 + so);
            b0 = *(const short8*)(vs + so);
            b1 = *(const short8*)(vs + 2048 + so);
        }

        short8 kf[2][4];
#pragma unroll
        for (int mt = 0; mt < 2; mt++)
#pragma unroll
            for (int kc = 0; kc < 4; kc++)
                kf[mt][kc] = *(const short8*)(kb[cur] + mt * 2048 + kc * 512 + fo);
        float16v s0a = {}, s1a = {}, s0b = {}, s1b = {};
#pragma unroll
        for (int kc = 0; kc < 4; kc++) {
            s0a = __builtin_amdgcn_mfma_f32_32x32x16_bf16(kf[0][kc], qfa[kc], s0a, 0, 0, 0);
            s1a = __builtin_amdgcn_mfma_f32_32x32x16_bf16(kf[1][kc], qfa[kc], s1a, 0, 0, 0);
            s0b = __builtin_amdgcn_mfma_f32_32x32x16_bf16(kf[0][kc], qfb[kc], s0b, 0, 0, 0);
            s1b = __builtin_amdgcn_mfma_f32_32x32x16_bf16(kf[1][kc], qfb[kc], s1b, 0, 0, 0);
        }
        short8 vf[2][4];
#pragma unroll
        for (int mt = 0; mt < 2; mt++)
#pragma unroll
            for (int kc = 0; kc < 4; kc++)
                vf[mt][kc] = *(const short8*)(vb[cur] + mt * 2048 + kc * 512 + fo);

        unsigned pk0a[8], pk1a[8], pk0b[8], pk1b[8];
#pragma unroll
        for (int j2 = 0; j2 < 8; j2++) {
            pk0a[j2] = pk2(__builtin_amdgcn_exp2f(s0a[2 * j2]),
                           __builtin_amdgcn_exp2f(s0a[2 * j2 + 1]));
            pk1a[j2] = pk2(__builtin_amdgcn_exp2f(s1a[2 * j2]),
                           __builtin_amdgcn_exp2f(s1a[2 * j2 + 1]));
            pk0b[j2] = pk2(__builtin_amdgcn_exp2f(s0b[2 * j2]),
                           __builtin_amdgcn_exp2f(s0b[2 * j2 + 1]));
            pk1b[j2] = pk2(__builtin_amdgcn_exp2f(s1b[2 * j2]),
                           __builtin_amdgcn_exp2f(s1b[2 * j2 + 1]));
        }
#pragma unroll
        for (int kc = 0; kc < 4; kc++) {
            const unsigned* pma = (kc < 2) ? pk0a : pk1a;
            const unsigned* pmb = (kc < 2) ? pk0b : pk1b;
            short8 bfa = pk_frag(pma, kc & 1);
            short8 bfb = pk_frag(pmb, kc & 1);
            Laa = __builtin_amdgcn_mfma_f32_32x32x16_bf16(ones.v, bfa, Laa, 0, 0, 0);
            O0a = __builtin_amdgcn_mfma_f32_32x32x16_bf16(vf[0][kc], bfa, O0a, 0, 0, 0);
            O1a = __builtin_amdgcn_mfma_f32_32x32x16_bf16(vf[1][kc], bfa, O1a, 0, 0, 0);
            Lab = __builtin_amdgcn_mfma_f32_32x32x16_bf16(ones.v, bfb, Lab, 0, 0, 0);
            O0b = __builtin_amdgcn_mfma_f32_32x32x16_bf16(vf[0][kc], bfb, O0b, 0, 0, 0);
            O1b = __builtin_amdgcn_mfma_f32_32x32x16_bf16(vf[1][kc], bfb, O1b, 0, 0, 0);
        }

        // write-late: park next tile in the other buffer, then barrier
        if (it < 15) {
            *(short8*)(kb[nxt] + so) = a0; *(short8*)(kb[nxt] + 2048 + so) = a1;
            *(short8*)(vb[nxt] + so) = b0; *(short8*)(vb[nxt] + 2048 + so) = b1;
        }
        __syncthreads();
    }

    // ---- epilogue: raw C-frag (pi-permuted d slots), b128 stores, 2 qt ----
    if (h == 0) {
        lbuf[(size_t)ksp * 65536 + bh * 2048 + qt0 * 32 + l31] = Laa[0];
        lbuf[(size_t)ksp * 65536 + bh * 2048 + (qt0 + 1) * 32 + l31] = Lab[0];
    }
#pragma unroll
    for (int j = 0; j < 2; j++) {
        ushort* ob = Opart + (size_t)ksp * 4194304 + ((size_t)bh * 64 + qt0 + j) * 2048;
#pragma unroll
        for (int mt = 0; mt < 2; mt++) {
            float16v Ov = j ? (mt ? O1b : O0b) : (mt ? O1a : O0a);
            unsigned pkO[8];
#pragma unroll
            for (int j2 = 0; j2 < 8; j2++) pkO[j2] = pk2(Ov[2 * j2], Ov[2 * j2 + 1]);
#pragma unroll
            for (int cc = 0; cc < 2; cc++)
                *(short8*)(ob + ((mt * 2 + cc) * 2 + h) * 256 + l31 * 8) =
                    pk_frag(pkO, cc);
        }
    }
}

// ---------------------------------------------------------------------------
// backf (fused back1 + back2): one block per rg (grid 128, 16 waves).
// Phase 1 (back1 math, hd = wave): per-head O-sum/normalize + MFMA vs bF
// proj-3. Phase 2: cross-wave reduce in BIT-IDENTICAL association —
// hq_i = (w4i + w4i+1) + (w4i+2 + w4i+3)  [back1's intra-block pairing],
// cf   = (hq0 + hq1) + (hq2 + hq3)        [back2's hq pairing],
// pack pk2 once into a 2 KB table, redistribute; each wave emits 2 nt
// tiles (back2's exact epilogue). Eliminates respart2 write + 8x redundant
// reads/reduction + one launch.
// ---------------------------------------------------------------------------
__global__ __launch_bounds__(1024) void backf_kern(const ushort* __restrict__ Opart,
                                                   const float* __restrict__ lbuf,
                                                   const ushort* __restrict__ bF,
                                                   const ushort* __restrict__ wobF,
                                                   float* __restrict__ out) {
    __shared__ float red[16 * 1024];         // 64 KB
    __shared__ unsigned pkrL[512];           // 2 KB
    const int t = threadIdx.x, wave = t >> 6, lane = t & 63;
    const int l31 = lane & 31, h = lane >> 5;
    const int rg = blockIdx.x;               // 0..127
    const int b = rg >> 6, qt = rg & 63;
    const int bh = b * NH + wave;            // head = wave (0..15)

    // ---- phase 1: back1's per-head math (hd = wave) ----
    float lb = lbuf[(size_t)bh * 2048 + qt * 32 + l31] +
               lbuf[(size_t)65536 + (size_t)bh * 2048 + qt * 32 + l31];
    float invl = 1.0f / lb;
    const ushort* ob0 = Opart + ((size_t)bh * 64 + qt) * 2048;
    const ushort* ob1 = ob0 + 4194304;

    float16v c = {};
#pragma unroll
    for (int kc = 0; kc < 4; kc++) {
        short8 o0 = *(const short8*)(ob0 + (kc * 2 + h) * 256 + l31 * 8);
        short8 o1 = *(const short8*)(ob1 + (kc * 2 + h) * 256 + l31 * 8);
        float av[8];
#pragma unroll
        for (int e = 0; e < 8; e++)
            av[e] = (ubf((ushort)o0[e]) + ubf((ushort)o1[e])) * invl;
        S8U bn;
        bn.u[0] = make_uint2(pk2(av[0], av[1]), pk2(av[2], av[3]));
        bn.u[1] = make_uint2(pk2(av[4], av[5]), pk2(av[6], av[7]));
        int kcg = wave * 4 + kc;             // global channel chunk 0..63
        short8 a = *(const short8*)(bF + ((size_t)((3 * 64 + kcg) * 2 + h) * 32 + l31) * 8);
        c = __builtin_amdgcn_mfma_f32_32x32x16_bf16(a, bn.v, c, 0, 0, 0);
    }
#pragma unroll
    for (int r = 0; r < 16; r++) red[wave * 1024 + r * 64 + lane] = c[r];
    __syncthreads();

    // ---- phase 2a: reduce + pack (bit-identical association) ----
    if (t < 512) {
        int j = t >> 6, ln = t & 63;         // j 0..7, ln 0..63
        float cf2[2];
#pragma unroll
        for (int s2 = 0; s2 < 2; s2++) {
            int off = (2 * j + s2) * 64 + ln;
            float hq0 = (red[0 * 1024 + off] + red[1 * 1024 + off]) +
                        (red[2 * 1024 + off] + red[3 * 1024 + off]);
            float hq1 = (red[4 * 1024 + off] + red[5 * 1024 + off]) +
                        (red[6 * 1024 + off] + red[7 * 1024 + off]);
            float hq2 = (red[8 * 1024 + off] + red[9 * 1024 + off]) +
                        (red[10 * 1024 + off] + red[11 * 1024 + off]);
            float hq3 = (red[12 * 1024 + off] + red[13 * 1024 + off]) +
                        (red[14 * 1024 + off] + red[15 * 1024 + off]);
            cf2[s2] = (hq0 + hq1) + (hq2 + hq3);
        }
        pkrL[j * 64 + ln] = pk2(cf2[0], cf2[1]);
    }
    __syncthreads();

    // ---- phase 2b: back2's epilogue, 2 nt tiles per wave ----
    unsigned pkr[8];
#pragma unroll
    for (int j = 0; j < 8; j++) pkr[j] = pkrL[j * 64 + lane];
    short8 a0 = pk_frag(pkr, 0);
    short8 a1 = pk_frag(pkr, 1);

#pragma unroll
    for (int i = 0; i < 2; i++) {
        int nt = wave * 2 + i;               // 0..31
        const ushort* wp = wobF + (size_t)nt * 1024;   // [kc2][h][l31][8]
        short8 wf0 = *(const short8*)(wp + (size_t)h * 256 + l31 * 8);
        short8 wf1 = *(const short8*)(wp + (size_t)(2 + h) * 256 + l31 * 8);
        float16v co = {};
        co = __builtin_amdgcn_mfma_f32_32x32x16_bf16(a0, wf0, co, 0, 0, 0);
        co = __builtin_amdgcn_mfma_f32_32x32x16_bf16(a1, wf1, co, 0, 0, 0);
#pragma unroll
        for (int r = 0; r < 16; r++) {
            int row = rg * 32 + crow(r, h);
            out[(size_t)row * CD + nt * 32 + l31] = co[r];
        }
    }
}

// ---------------------------------------------------------------------------
extern "C" void kernel_launch(void* const* d_in, const int* in_sizes, int n_in,
                              void* d_out, int out_size, void* d_ws, size_t ws_size,
                              hipStream_t stream) {
    const float* x  = (const float*)d_in[0];
    const float* bq = (const float*)d_in[1];
    const float* pq = (const float*)d_in[2];
    const float* aq = (const float*)d_in[3];
    const float* bk = (const float*)d_in[4];
    const float* pk = (const float*)d_in[5];
    const float* ak = (const float*)d_in[6];
    const float* bv = (const float*)d_in[7];
    const float* pv = (const float*)d_in[8];
    const float* av = (const float*)d_in[9];
    const float* bo = (const float*)d_in[10];
    const float* po = (const float*)d_in[11];
    const float* ao = (const float*)d_in[12];

    char* ws = (char*)d_ws;
    ushort* bF      = (ushort*)(ws + 0);          // 256 KB
    ushort* wqkvF   = (ushort*)(ws + 262144);     // 192 KB
    ushort* wobF    = (ushort*)(ws + 458752);     //  64 KB
    ushort* qtile   = (ushort*)(ws + 524288);     //   8 MB
    ushort* ktile   = (ushort*)(ws + 8912896);    //   8 MB
    ushort* vtile   = (ushort*)(ws + 17301504);   //   8 MB
    ushort* Opart   = (ushort*)(ws + 25690112);   //  16 MB (2 ksp x 8 MB, bf16)
    float*  lbuf    = (float*)(ws + 42467328);    // 512 KB
    unsigned* rfbuf = (unsigned*)(ws + 25690112); // 768 KB alias of Opart (safe:
                                                  //   resrp writes + qkv reads BEFORE
                                                  //   flash8 overwrites Opart)

    prep_kern<<<128, 256, 0, stream>>>(bq, bk, bv, bo, pq, aq, pk, ak, pv, av,
                                       po, ao, bF, wqkvF, wobF);
    resrp_kern<<<128, 512, 0, stream>>>(x, bF, rfbuf);
    qkv_kern<<<3072, 256, 0, stream>>>(rfbuf, wqkvF, qtile, ktile, vtile);
    flash8<<<512, 256, 0, stream>>>(qtile, ktile, vtile, Opart, lbuf);
    backf_kern<<<128, 1024, 0, stream>>>(Opart, lbuf, bF, wobF, (float*)d_out);
}

// Round 23
// 145.277 us; speedup vs baseline: 1.0602x; 1.0210x over previous
//
#include <hip/hip_runtime.h>
#include <hip/hip_bf16.h>
#include <cstdint>
#include <cstddef>

#define NH   16
#define HD   64
#define CD   1024
#define HARM 32
#define BSZ  2
#define LSEQ 2048
#define NROW (BSZ*LSEQ)   // 4096

typedef __attribute__((ext_vector_type(8))) short short8;     // 8 bf16 (A/B frag)
typedef __attribute__((ext_vector_type(16))) float float16v;  // 32x32 C frag

__device__ inline ushort bf16u(float f) {
    __hip_bfloat16 h = __float2bfloat16(f);
    return *(ushort*)&h;
}
__device__ inline float ubf(ushort u) {
    return __uint_as_float((unsigned)u << 16);
}
__device__ inline unsigned pk2(float a, float b) {
    return (unsigned)bf16u(a) | ((unsigned)bf16u(b) << 16);
}
// C-frag register r -> row offset within 32-row tile
__device__ inline int crow(int r, int half) { return (r & 3) + 8 * (r >> 2) + 4 * half; }

union S8U { short8 v; uint2 u[2]; };

// pi-permuted operand frag: raw packed C-frag regs for 16-k chunk cc.
// Slot (h,e) holds k = (e&3)+8*(e>>2)+4h (the involution pi). Valid as an
// MFMA A/B operand whenever the OTHER operand carries the same pi in its
// k-slots (pre-baked into weight tiles at prep, or raw C-frag on both sides).
__device__ inline short8 pk_frag(const unsigned* pk, int cc) {
    S8U o;
    o.u[0] = make_uint2(pk[4 * cc + 0], pk[4 * cc + 1]);
    o.u[1] = make_uint2(pk[4 * cc + 2], pk[4 * cc + 3]);
    return o.v;
}

// ---------------------------------------------------------------------------
// prep: fragment-tile all weights.
//   bF proj 0..2: STANDARD slot order (pairs with x-chunks in resrp).
//   bF proj 3, wqkvF, wobF: pi-permuted slot order (pair with raw C-frags).
// ---------------------------------------------------------------------------
__global__ void prep_kern(const float* __restrict__ bq, const float* __restrict__ bk,
                          const float* __restrict__ bv, const float* __restrict__ bo,
                          const float* __restrict__ pq, const float* __restrict__ aq,
                          const float* __restrict__ pk, const float* __restrict__ ak,
                          const float* __restrict__ pv, const float* __restrict__ av,
                          const float* __restrict__ po, const float* __restrict__ ao,
                          ushort* __restrict__ bF, ushort* __restrict__ wqkvF,
                          ushort* __restrict__ wobF) {
    const float QSCALE = 0.125f * 1.44269504088896340736f;  // hd^-0.5 * log2e
    unsigned tid = blockIdx.x * 256 + threadIdx.x;
    if (tid < 16384) {                 // bF
        unsigned l31 = tid & 31, h = (tid >> 5) & 1, kc = (tid >> 6) & 63, proj = tid >> 12;
        const float* bp = (proj == 0) ? bq : (proj == 1) ? bk : (proj == 2) ? bv : bo;
        const float* s = bp + (size_t)l31 * CD + kc * 16;
        // proj 3 permuted: elements {4h..4h+3, 8+4h..8+4h+3}; else {8h..8h+7}
        unsigned o0 = (proj == 3) ? h * 4 : h * 8;
        unsigned o1 = o0 + ((proj == 3) ? 8 : 4);
        float4 f0 = *(const float4*)(s + o0), f1 = *(const float4*)(s + o1);
        S8U o;
        o.u[0] = make_uint2(pk2(f0.x, f0.y), pk2(f0.z, f0.w));
        o.u[1] = make_uint2(pk2(f1.x, f1.y), pk2(f1.z, f1.w));
        *(short8*)(bF + (size_t)tid * 8) = o.v;
        return;
    }
    if (tid < 28672) {                 // wqkvF (pi-permuted harmonic slots)
        unsigned i = tid - 16384;
        unsigned l31 = i & 31, h = (i >> 5) & 1, kc2 = (i >> 6) & 1;
        unsigned ntp = (i >> 7) & 31, proj = i >> 12;
        const float* ph = (proj == 0) ? pq : (proj == 1) ? pk : pv;
        const float* am = (proj == 0) ? aq : (proj == 1) ? ak : av;
        float sc = (proj == 0) ? QSCALE : 1.0f;
        size_t s = (size_t)(ntp * 32 + l31) * HARM + kc2 * 16 + h * 4;
        float4 p0 = *(const float4*)(ph + s), p1 = *(const float4*)(ph + s + 8);
        float4 a0 = *(const float4*)(am + s), a1 = *(const float4*)(am + s + 8);
        S8U o;
        o.u[0] = make_uint2(pk2(a0.x * cosf(p0.x) * sc, a0.y * cosf(p0.y) * sc),
                            pk2(a0.z * cosf(p0.z) * sc, a0.w * cosf(p0.w) * sc));
        o.u[1] = make_uint2(pk2(a1.x * cosf(p1.x) * sc, a1.y * cosf(p1.y) * sc),
                            pk2(a1.z * cosf(p1.z) * sc, a1.w * cosf(p1.w) * sc));
        *(short8*)(wqkvF + (size_t)i * 8) = o.v;
        return;
    }
    {                                  // wobF (pi-permuted harmonic slots)
        unsigned i = tid - 28672;      // 4096
        unsigned l31 = i & 31, h = (i >> 5) & 1, kc2 = (i >> 6) & 1, nt = i >> 7;
        size_t s = (size_t)(nt * 32 + l31) * HARM + kc2 * 16 + h * 4;
        float4 p0 = *(const float4*)(po + s), p1 = *(const float4*)(po + s + 8);
        float4 a0 = *(const float4*)(ao + s), a1 = *(const float4*)(ao + s + 8);
        S8U o;
        o.u[0] = make_uint2(pk2(a0.x * cosf(p0.x), a0.y * cosf(p0.y)),
                            pk2(a0.z * cosf(p0.z), a0.w * cosf(p0.w)));
        o.u[1] = make_uint2(pk2(a1.x * cosf(p1.x), a1.y * cosf(p1.y)),
                            pk2(a1.z * cosf(p1.z), a1.w * cosf(p1.w)));
        *(short8*)(wobF + (size_t)i * 8) = o.v;
    }
}

// ---------------------------------------------------------------------------
// resrp (fused res_part + rp, verified round 20 — bit-identical absmax).
// ---------------------------------------------------------------------------
__global__ __launch_bounds__(512) void resrp_kern(const float* __restrict__ x,
                                                  const ushort* __restrict__ bF,
                                                  unsigned* __restrict__ rfbuf) {
    __shared__ ushort xs[4][8192];           // 64 KB  [kseg][row*256+chunk*8+sub*4]
    float* red = (float*)xs;                 // aliases xs: 8 waves x 1024 = 32 KB
    const int t = threadIdx.x, wave = t >> 6, lane = t & 63;
    const int l31 = lane & 31, h = lane >> 5;
    const int rest = blockIdx.x;             // 0..127
    const int n0 = rest * 32;

    // stage all 4 ksegs: 16 coalesced float4 loads per thread
#pragma unroll
    for (int i = 0; i < 16; i++) {
        int idx = i * 512 + t;               // 0..8191 float4 slots
        int row = idx >> 8, c4g = idx & 255;
        int kseg = c4g >> 6, c4 = c4g & 63;
        float4 v = *(const float4*)(x + (size_t)(n0 + row) * CD + kseg * 256 + c4 * 4);
        int chunk = (c4 >> 1) ^ (row & 15), sub = c4 & 1;
        *(ushort4*)(&xs[kseg][row * 256 + chunk * 8 + sub * 4]) =
            make_ushort4(bf16u(v.x), bf16u(v.y), bf16u(v.z), bf16u(v.w));
    }
    __syncthreads();

    float16v resC[3] = {};
#pragma unroll
    for (int i = 0; i < 8; i++) {
        int kcg = wave * 8 + i;              // 0..63
        int kseg = kcg >> 4, m = kcg & 15;
        int c = m * 2 + h;
        short8 bx = *(const short8*)(&xs[kseg][l31 * 256 + ((c ^ (l31 & 15)) * 8)]);
#pragma unroll
        for (int p = 0; p < 3; p++) {
            short8 a = *(const short8*)(bF + ((size_t)((p * 64 + kcg) * 2 + h) * 32 + l31) * 8);
            resC[p] = __builtin_amdgcn_mfma_f32_32x32x16_bf16(a, bx, resC[p], 0, 0, 0);
        }
    }

    unsigned* ob = rfbuf + (size_t)rest * 1536;
    for (int p = 0; p < 3; p++) {
        __syncthreads();                     // xs/red free (prev phase done)
#pragma unroll
        for (int r = 0; r < 16; r++) red[wave * 1024 + r * 64 + lane] = resC[p][r];
        __syncthreads();
        if (t < 128) {
            int cc = t >> 6, ln = t & 63;
            unsigned w[4];
#pragma unroll
            for (int q = 0; q < 4; q++) {
                int j = cc * 4 + q;
                float va = 0.0f, vb2 = 0.0f;
#pragma unroll
                for (int wv = 0; wv < 8; wv++) {
                    va  += red[wv * 1024 + (2 * j) * 64 + ln];
                    vb2 += red[wv * 1024 + (2 * j + 1) * 64 + ln];
                }
                w[q] = pk2(va, vb2);
            }
            *(uint4*)(ob + ((p * 2 + cc) * 64 + ln) * 4) =
                make_uint4(w[0], w[1], w[2], w[3]);
        }
    }
}

// ---------------------------------------------------------------------------
// qkv v4: pure phase-2 (verified round 8).
// ---------------------------------------------------------------------------
__global__ __launch_bounds__(256) void qkv_kern(const unsigned* __restrict__ rfbuf,
                                                const ushort* __restrict__ wqkvF,
                                                ushort* __restrict__ qtile,
                                                ushort* __restrict__ ktile,
                                                ushort* __restrict__ vtile) {
    const int t = threadIdx.x, wave = t >> 6, lane = t & 63;
    const int l31 = lane & 31, h = lane >> 5;
    const int ntg = blockIdx.x % 24, rest = blockIdx.x / 24;
    const int b = rest >> 6, l0q = rest & 63;
    const int nt = ntg * 4 + wave;               // 0..95
    const int proj = nt >> 5, ntp = nt & 31;
    const int head = ntp >> 1, sub = ntp & 1;
    const int kblk = l0q >> 1, mtk = l0q & 1;

    const unsigned* rb = rfbuf + (size_t)rest * 1536 + ((proj * 2) * 64 + lane) * 4;
    uint4 q0 = *(const uint4*)(rb);
    uint4 q1 = *(const uint4*)(rb + 256);
    S8U r0, r1;
    r0.u[0] = make_uint2(q0.x, q0.y); r0.u[1] = make_uint2(q0.z, q0.w);
    r1.u[0] = make_uint2(q1.x, q1.y); r1.u[1] = make_uint2(q1.z, q1.w);

    const ushort* wp = wqkvF + ((size_t)(proj * 32 + ntp) * 4) * 256;  // [kc2][h][l31][8]
    short8 wf0 = *(const short8*)(wp + (size_t)h * 256 + l31 * 8);
    short8 wf1 = *(const short8*)(wp + (size_t)(2 + h) * 256 + l31 * 8);
    float16v c = {};
    if (proj < 2) {   // A=w (lane=ch), B=res (lane=row) -> C col=row
        c = __builtin_amdgcn_mfma_f32_32x32x16_bf16(wf0, r0.v, c, 0, 0, 0);
        c = __builtin_amdgcn_mfma_f32_32x32x16_bf16(wf1, r1.v, c, 0, 0, 0);
    } else {          // A=res (lane=row), B=w (lane=ch) -> C col=ch
        c = __builtin_amdgcn_mfma_f32_32x32x16_bf16(r0.v, wf0, c, 0, 0, 0);
        c = __builtin_amdgcn_mfma_f32_32x32x16_bf16(r1.v, wf1, c, 0, 0, 0);
    }
    unsigned pkc[8];
#pragma unroll
    for (int j = 0; j < 8; j++) pkc[j] = pk2(c[2 * j], c[2 * j + 1]);

    if (proj == 0) {
        ushort* base = qtile + (((size_t)(b * NH + head) * 64 + l0q)) * 2048;
#pragma unroll
        for (int cc = 0; cc < 2; cc++)
            *(short8*)(base + (sub * 2 + cc) * 512 + h * 256 + l31 * 8) =
                pk_frag(pkc, cc);
    } else if (proj == 1) {
        ushort* base = ktile + ((size_t)(b * NH + head) * 32 + kblk) * 4096 + mtk * 2048;
#pragma unroll
        for (int cc = 0; cc < 2; cc++)
            *(short8*)(base + (sub * 2 + cc) * 512 + h * 256 + l31 * 8) =
                pk_frag(pkc, cc);
    } else {
        ushort* base = vtile + ((size_t)(b * NH + head) * 32 + kblk) * 4096 + sub * 2048;
#pragma unroll
        for (int cc = 0; cc < 2; cc++)
            *(short8*)(base + (mtk * 2 + cc) * 512 + h * 256 + l31 * 8) =
                pk_frag(pkc, cc);
    }
}

// ---------------------------------------------------------------------------
// flash8 v10: v6 math/order, but TWO kblks per barrier. LDS doubles to
// 64 KB (kb/vb[2][2]); 2 blocks/CU x 64 KB = 128 <= 160 so occupancy is
// unchanged (unlike m132's regression). Per super-iter: issue next pair's
// 8 staged loads, run two full kblk bodies (~2600 cyc, covers load
// latency 5x), park both, ONE barrier. Barrier drains/block: 16 -> 8.
// Per-kblk math identical -> bit-identical output.
// ---------------------------------------------------------------------------
__global__ __launch_bounds__(256, 2) void flash8(const ushort* __restrict__ qtile,
                                                 const ushort* __restrict__ ktile,
                                                 const ushort* __restrict__ vtile,
                                                 ushort* __restrict__ Opart,
                                                 float* __restrict__ lbuf) {
    __shared__ ushort kb[2][2][4096];        // 32 KB
    __shared__ ushort vb[2][2][4096];        // 32 KB
    const int t = threadIdx.x;
    const int wave = t >> 6, lane = t & 63;
    const int l31 = lane & 31, h = lane >> 5;
    const int d = blockIdx.x;                      // 512 blocks
    const int logical = (d & 7) * 64 + (d >> 3);   // XCD x owns bh [4x,4x+4)
    const int bh = logical >> 4;
    const int inner = logical & 15;
    const int ksp = inner >> 3;
    const int qtg = inner & 7;
    const int qt0 = qtg * 8 + wave * 2;            // wave owns qt0, qt0+1
    const int fo = h * 256 + l31 * 8;
    const int so = t * 8;                          // 16B per thread staging slot

    const ushort* qtb = qtile + ((size_t)bh * 64 + qt0) * 2048;
    short8 qfa[4], qfb[4];
#pragma unroll
    for (int kc = 0; kc < 4; kc++) {
        qfa[kc] = *(const short8*)(qtb + kc * 512 + fo);
        qfb[kc] = *(const short8*)(qtb + 2048 + kc * 512 + fo);
    }

    const ushort* ktb = ktile + (size_t)bh * 32 * 4096;
    const ushort* vtb = vtile + (size_t)bh * 32 * 4096;
    const int k0 = ksp * 16;

    // prologue: stage kblk pair (k0, k0+1) into buffer 0
    {
#pragma unroll
        for (int s = 0; s < 2; s++) {
            const ushort* ks = ktb + (size_t)(k0 + s) * 4096;
            const ushort* vs = vtb + (size_t)(k0 + s) * 4096;
            short8 a0 = *(const short8*)(ks + so);
            short8 a1 = *(const short8*)(ks + 2048 + so);
            short8 b0 = *(const short8*)(vs + so);
            short8 b1 = *(const short8*)(vs + 2048 + so);
            *(short8*)(kb[0][s] + so) = a0; *(short8*)(kb[0][s] + 2048 + so) = a1;
            *(short8*)(vb[0][s] + so) = b0; *(short8*)(vb[0][s] + 2048 + so) = b1;
        }
    }
    __syncthreads();

    S8U ones;
    ones.u[0] = make_uint2(0x3F803F80u, 0x3F803F80u);
    ones.u[1] = make_uint2(0x3F803F80u, 0x3F803F80u);

    float16v O0a = {}, O1a = {}, Laa = {};
    float16v O0b = {}, O1b = {}, Lab = {};

#pragma unroll
    for (int ii = 0; ii < 8; ii++) {
        const int cur = ii & 1, nxt = cur ^ 1;

        // T14 issue-early: next PAIR's global loads start now
        short8 ka[2][2], va[2][2];
        if (ii < 7) {
#pragma unroll
            for (int s = 0; s < 2; s++) {
                const ushort* ks = ktb + (size_t)(k0 + 2 * (ii + 1) + s) * 4096;
                const ushort* vs = vtb + (size_t)(k0 + 2 * (ii + 1) + s) * 4096;
                ka[s][0] = *(const short8*)(ks + so);
                ka[s][1] = *(const short8*)(ks + 2048 + so);
                va[s][0] = *(const short8*)(vs + so);
                va[s][1] = *(const short8*)(vs + 2048 + so);
            }
        }

        // two full kblk bodies (v6 math, unchanged order within each)
#pragma unroll
        for (int s = 0; s < 2; s++) {
            short8 kf[2][4];
#pragma unroll
            for (int mt = 0; mt < 2; mt++)
#pragma unroll
                for (int kc = 0; kc < 4; kc++)
                    kf[mt][kc] = *(const short8*)(kb[cur][s] + mt * 2048 + kc * 512 + fo);
            float16v s0a = {}, s1a = {}, s0b = {}, s1b = {};
#pragma unroll
            for (int kc = 0; kc < 4; kc++) {
                s0a = __builtin_amdgcn_mfma_f32_32x32x16_bf16(kf[0][kc], qfa[kc], s0a, 0, 0, 0);
                s1a = __builtin_amdgcn_mfma_f32_32x32x16_bf16(kf[1][kc], qfa[kc], s1a, 0, 0, 0);
                s0b = __builtin_amdgcn_mfma_f32_32x32x16_bf16(kf[0][kc], qfb[kc], s0b, 0, 0, 0);
                s1b = __builtin_amdgcn_mfma_f32_32x32x16_bf16(kf[1][kc], qfb[kc], s1b, 0, 0, 0);
            }
            short8 vf[2][4];
#pragma unroll
            for (int mt = 0; mt < 2; mt++)
#pragma unroll
                for (int kc = 0; kc < 4; kc++)
                    vf[mt][kc] = *(const short8*)(vb[cur][s] + mt * 2048 + kc * 512 + fo);

            unsigned pk0a[8], pk1a[8], pk0b[8], pk1b[8];
#pragma unroll
            for (int j2 = 0; j2 < 8; j2++) {
                pk0a[j2] = pk2(__builtin_amdgcn_exp2f(s0a[2 * j2]),
                               __builtin_amdgcn_exp2f(s0a[2 * j2 + 1]));
                pk1a[j2] = pk2(__builtin_amdgcn_exp2f(s1a[2 * j2]),
                               __builtin_amdgcn_exp2f(s1a[2 * j2 + 1]));
                pk0b[j2] = pk2(__builtin_amdgcn_exp2f(s0b[2 * j2]),
                               __builtin_amdgcn_exp2f(s0b[2 * j2 + 1]));
                pk1b[j2] = pk2(__builtin_amdgcn_exp2f(s1b[2 * j2]),
                               __builtin_amdgcn_exp2f(s1b[2 * j2 + 1]));
            }
#pragma unroll
            for (int kc = 0; kc < 4; kc++) {
                const unsigned* pma = (kc < 2) ? pk0a : pk1a;
                const unsigned* pmb = (kc < 2) ? pk0b : pk1b;
                short8 bfa = pk_frag(pma, kc & 1);
                short8 bfb = pk_frag(pmb, kc & 1);
                Laa = __builtin_amdgcn_mfma_f32_32x32x16_bf16(ones.v, bfa, Laa, 0, 0, 0);
                O0a = __builtin_amdgcn_mfma_f32_32x32x16_bf16(vf[0][kc], bfa, O0a, 0, 0, 0);
                O1a = __builtin_amdgcn_mfma_f32_32x32x16_bf16(vf[1][kc], bfa, O1a, 0, 0, 0);
                Lab = __builtin_amdgcn_mfma_f32_32x32x16_bf16(ones.v, bfb, Lab, 0, 0, 0);
                O0b = __builtin_amdgcn_mfma_f32_32x32x16_bf16(vf[0][kc], bfb, O0b, 0, 0, 0);
                O1b = __builtin_amdgcn_mfma_f32_32x32x16_bf16(vf[1][kc], bfb, O1b, 0, 0, 0);
            }
        }

        // write-late: park next pair in the other buffer, then ONE barrier
        if (ii < 7) {
#pragma unroll
            for (int s = 0; s < 2; s++) {
                *(short8*)(kb[nxt][s] + so) = ka[s][0];
                *(short8*)(kb[nxt][s] + 2048 + so) = ka[s][1];
                *(short8*)(vb[nxt][s] + so) = va[s][0];
                *(short8*)(vb[nxt][s] + 2048 + so) = va[s][1];
            }
        }
        __syncthreads();
    }

    // ---- epilogue: raw C-frag (pi-permuted d slots), b128 stores, 2 qt ----
    if (h == 0) {
        lbuf[(size_t)ksp * 65536 + bh * 2048 + qt0 * 32 + l31] = Laa[0];
        lbuf[(size_t)ksp * 65536 + bh * 2048 + (qt0 + 1) * 32 + l31] = Lab[0];
    }
#pragma unroll
    for (int j = 0; j < 2; j++) {
        ushort* ob = Opart + (size_t)ksp * 4194304 + ((size_t)bh * 64 + qt0 + j) * 2048;
#pragma unroll
        for (int mt = 0; mt < 2; mt++) {
            float16v Ov = j ? (mt ? O1b : O0b) : (mt ? O1a : O0a);
            unsigned pkO[8];
#pragma unroll
            for (int j2 = 0; j2 < 8; j2++) pkO[j2] = pk2(Ov[2 * j2], Ov[2 * j2 + 1]);
#pragma unroll
            for (int cc = 0; cc < 2; cc++)
                *(short8*)(ob + ((mt * 2 + cc) * 2 + h) * 256 + l31 * 8) =
                    pk_frag(pkO, cc);
        }
    }
}

// ---------------------------------------------------------------------------
// backf (fused back1 + back2, verified round 21 — bit-identical absmax).
// ---------------------------------------------------------------------------
__global__ __launch_bounds__(1024) void backf_kern(const ushort* __restrict__ Opart,
                                                   const float* __restrict__ lbuf,
                                                   const ushort* __restrict__ bF,
                                                   const ushort* __restrict__ wobF,
                                                   float* __restrict__ out) {
    __shared__ float red[16 * 1024];         // 64 KB
    __shared__ unsigned pkrL[512];           // 2 KB
    const int t = threadIdx.x, wave = t >> 6, lane = t & 63;
    const int l31 = lane & 31, h = lane >> 5;
    const int rg = blockIdx.x;               // 0..127
    const int b = rg >> 6, qt = rg & 63;
    const int bh = b * NH + wave;            // head = wave (0..15)

    // ---- phase 1: back1's per-head math (hd = wave) ----
    float lb = lbuf[(size_t)bh * 2048 + qt * 32 + l31] +
               lbuf[(size_t)65536 + (size_t)bh * 2048 + qt * 32 + l31];
    float invl = 1.0f / lb;
    const ushort* ob0 = Opart + ((size_t)bh * 64 + qt) * 2048;
    const ushort* ob1 = ob0 + 4194304;

    float16v c = {};
#pragma unroll
    for (int kc = 0; kc < 4; kc++) {
        short8 o0 = *(const short8*)(ob0 + (kc * 2 + h) * 256 + l31 * 8);
        short8 o1 = *(const short8*)(ob1 + (kc * 2 + h) * 256 + l31 * 8);
        float av[8];
#pragma unroll
        for (int e = 0; e < 8; e++)
            av[e] = (ubf((ushort)o0[e]) + ubf((ushort)o1[e])) * invl;
        S8U bn;
        bn.u[0] = make_uint2(pk2(av[0], av[1]), pk2(av[2], av[3]));
        bn.u[1] = make_uint2(pk2(av[4], av[5]), pk2(av[6], av[7]));
        int kcg = wave * 4 + kc;             // global channel chunk 0..63
        short8 a = *(const short8*)(bF + ((size_t)((3 * 64 + kcg) * 2 + h) * 32 + l31) * 8);
        c = __builtin_amdgcn_mfma_f32_32x32x16_bf16(a, bn.v, c, 0, 0, 0);
    }
#pragma unroll
    for (int r = 0; r < 16; r++) red[wave * 1024 + r * 64 + lane] = c[r];
    __syncthreads();

    // ---- phase 2a: reduce + pack (bit-identical association) ----
    if (t < 512) {
        int j = t >> 6, ln = t & 63;         // j 0..7, ln 0..63
        float cf2[2];
#pragma unroll
        for (int s2 = 0; s2 < 2; s2++) {
            int off = (2 * j + s2) * 64 + ln;
            float hq0 = (red[0 * 1024 + off] + red[1 * 1024 + off]) +
                        (red[2 * 1024 + off] + red[3 * 1024 + off]);
            float hq1 = (red[4 * 1024 + off] + red[5 * 1024 + off]) +
                        (red[6 * 1024 + off] + red[7 * 1024 + off]);
            float hq2 = (red[8 * 1024 + off] + red[9 * 1024 + off]) +
                        (red[10 * 1024 + off] + red[11 * 1024 + off]);
            float hq3 = (red[12 * 1024 + off] + red[13 * 1024 + off]) +
                        (red[14 * 1024 + off] + red[15 * 1024 + off]);
            cf2[s2] = (hq0 + hq1) + (hq2 + hq3);
        }
        pkrL[j * 64 + ln] = pk2(cf2[0], cf2[1]);
    }
    __syncthreads();

    // ---- phase 2b: back2's epilogue, 2 nt tiles per wave ----
    unsigned pkr[8];
#pragma unroll
    for (int j = 0; j < 8; j++) pkr[j] = pkrL[j * 64 + lane];
    short8 a0 = pk_frag(pkr, 0);
    short8 a1 = pk_frag(pkr, 1);

#pragma unroll
    for (int i = 0; i < 2; i++) {
        int nt = wave * 2 + i;               // 0..31
        const ushort* wp = wobF + (size_t)nt * 1024;   // [kc2][h][l31][8]
        short8 wf0 = *(const short8*)(wp + (size_t)h * 256 + l31 * 8);
        short8 wf1 = *(const short8*)(wp + (size_t)(2 + h) * 256 + l31 * 8);
        float16v co = {};
        co = __builtin_amdgcn_mfma_f32_32x32x16_bf16(a0, wf0, co, 0, 0, 0);
        co = __builtin_amdgcn_mfma_f32_32x32x16_bf16(a1, wf1, co, 0, 0, 0);
#pragma unroll
        for (int r = 0; r < 16; r++) {
            int row = rg * 32 + crow(r, h);
            out[(size_t)row * CD + nt * 32 + l31] = co[r];
        }
    }
}

// ---------------------------------------------------------------------------
extern "C" void kernel_launch(void* const* d_in, const int* in_sizes, int n_in,
                              void* d_out, int out_size, void* d_ws, size_t ws_size,
                              hipStream_t stream) {
    const float* x  = (const float*)d_in[0];
    const float* bq = (const float*)d_in[1];
    const float* pq = (const float*)d_in[2];
    const float* aq = (const float*)d_in[3];
    const float* bk = (const float*)d_in[4];
    const float* pk = (const float*)d_in[5];
    const float* ak = (const float*)d_in[6];
    const float* bv = (const float*)d_in[7];
    const float* pv = (const float*)d_in[8];
    const float* av = (const float*)d_in[9];
    const float* bo = (const float*)d_in[10];
    const float* po = (const float*)d_in[11];
    const float* ao = (const float*)d_in[12];

    char* ws = (char*)d_ws;
    ushort* bF      = (ushort*)(ws + 0);          // 256 KB
    ushort* wqkvF   = (ushort*)(ws + 262144);     // 192 KB
    ushort* wobF    = (ushort*)(ws + 458752);     //  64 KB
    ushort* qtile   = (ushort*)(ws + 524288);     //   8 MB
    ushort* ktile   = (ushort*)(ws + 8912896);    //   8 MB
    ushort* vtile   = (ushort*)(ws + 17301504);   //   8 MB
    ushort* Opart   = (ushort*)(ws + 25690112);   //  16 MB (2 ksp x 8 MB, bf16)
    float*  lbuf    = (float*)(ws + 42467328);    // 512 KB
    unsigned* rfbuf = (unsigned*)(ws + 25690112); // 768 KB alias of Opart (safe:
                                                  //   resrp writes + qkv reads BEFORE
                                                  //   flash8 overwrites Opart)

    prep_kern<<<128, 256, 0, stream>>>(bq, bk, bv, bo, pq, aq, pk, ak, pv, av,
                                       po, ao, bF, wqkvF, wobF);
    resrp_kern<<<128, 512, 0, stream>>>(x, bF, rfbuf);
    qkv_kern<<<3072, 256, 0, stream>>>(rfbuf, wqkvF, qtile, ktile, vtile);
    flash8<<<512, 256, 0, stream>>>(qtile, ktile, vtile, Opart, lbuf);
    backf_kern<<<128, 1024, 0, stream>>>(Opart, lbuf, bF, wobF, (float*)d_out);
}